// Round 9
// baseline (1046.571 us; speedup 1.0000x reference)
//
#include <hip/hip_runtime.h>
#include <math.h>

#define NA 16384
#define ER 524288
#define EB 32768
#define ET 557056
#define INV_NORM 0.17149858514250882f   // 1/sqrt((ER+EB)/NA) = 1/sqrt(34)
#define SQRT3 1.7320508075688772f
#define RB_STEP (1.5f/9.0f)
#define BINS 512
#define DMAX 2.5f
#define INV_H ((float)BINS / DMAX)
#define TBL_ELEMS (2 * BINS * 256)   // one table: [2][BINS][64][4] floats

__device__ __forceinline__ float sigmoidf_(float x) { return 1.f / (1.f + __expf(-x)); }

__device__ __forceinline__ int edge_dst(int e, const int* __restrict__ rad, const int* __restrict__ bon) {
  return (e < ER) ? rad[ER + e] : bon[EB + (e - ER)];
}

// ---------------- CSR build ----------------
__global__ void k_zero(int* __restrict__ count) {
  count[blockIdx.x * 256 + threadIdx.x] = 0;
}

__global__ void k_hist(const int* __restrict__ rad, const int* __restrict__ bon, int* __restrict__ count) {
  int e = blockIdx.x * 256 + threadIdx.x;
  atomicAdd(&count[edge_dst(e, rad, bon)], 1);
}

__global__ void k_scan(int* __restrict__ count, int* __restrict__ offsets) {
  __shared__ int part[256];
  int t = threadIdx.x;
  int base = t * 64;
  int s = 0;
  for (int j = 0; j < 64; ++j) s += count[base + j];
  part[t] = s;
  __syncthreads();
  for (int off = 1; off < 256; off <<= 1) {
    int v = (t >= off) ? part[t - off] : 0;
    __syncthreads();
    part[t] += v;
    __syncthreads();
  }
  int run = part[t] - s;  // exclusive prefix
  for (int j = 0; j < 64; ++j) {
    int c = count[base + j];
    offsets[base + j] = run;
    count[base + j] = run;  // becomes cursor for k_fill
    run += c;
  }
  if (t == 255) offsets[NA] = run;
}

__global__ void k_fill(const int* __restrict__ rad, const int* __restrict__ bon,
                       int* __restrict__ cursor, int* __restrict__ sorted) {
  int e = blockIdx.x * 256 + threadIdx.x;
  int d = edge_dst(e, rad, bon);
  int slot = atomicAdd(&cursor[d], 1);
  sorted[slot] = e;
}

// ---------------- per-edge record precompute ----------------
// record[idx] (32B): {src, Y0, Y1, Y2, frac, qoff(elem offset into a table), pad, pad}
__global__ void k_edge_pre(const float* __restrict__ pos,
                           const int* __restrict__ rad, const int* __restrict__ bon,
                           const int* __restrict__ sorted, float* __restrict__ rec8) {
  int idx = blockIdx.x * 256 + threadIdx.x;
  int e = sorted[idx];
  int src, dst, v;
  if (e < ER) { src = rad[e]; dst = rad[ER + e]; v = 0; }
  else        { src = bon[e - ER]; dst = bon[EB + e - ER]; v = 1; }
  float dx = pos[src * 3] - pos[dst * 3];
  float dy = pos[src * 3 + 1] - pos[dst * 3 + 1];
  float dz = pos[src * 3 + 2] - pos[dst * 3 + 2];
  float dist = sqrtf(dx * dx + dy * dy + dz * dz + 1e-12f);
  float inv = 1.f / dist;
  float fq = fminf(dist * INV_H, BINS - 1.001f);
  int q = (int)fq;
  float frac = fq - (float)q;
  int qoff = (v * BINS + q) << 8;   // 256 floats per row
  float* rp = rec8 + (size_t)idx * 8;
  *(float4*)rp = make_float4(__int_as_float(src), SQRT3 * dx * inv, SQRT3 * dy * inv, SQRT3 * dz * inv);
  rp[4] = frac;
  rp[5] = __int_as_float(qoff);
}

// ---------------- radial-weight tables with bond base folded ----------------
__global__ void k_build(const float* __restrict__ We0, const float* __restrict__ We1,
                        const float* __restrict__ We_ss, const float* __restrict__ We_vs,
                        const float* __restrict__ We_sv, const float* __restrict__ We_vv,
                        const float* __restrict__ We_vx, const float* __restrict__ bond_tab,
                        float* __restrict__ tabs) {
  int q = blockIdx.x, t = blockIdx.y, v = blockIdx.z, c = threadIdx.x;
  float d0 = q * (DMAX / BINS), d1 = (q + 1) * (DMAX / BINS);
  float rb0[8], rb1[8];
#pragma unroll
  for (int k = 0; k < 8; ++k) {
    float f0 = (d0 - (k + 1) * RB_STEP) * (1.f / RB_STEP);
    float f1 = (d1 - (k + 1) * RB_STEP) * (1.f / RB_STEP);
    rb0[k] = 1.12f * __expf(-f0 * f0);
    rb1[k] = 1.12f * __expf(-f1 * f1);
  }
  const float* A;
  const float* B;
  int stride, coff;
  bool hasB = true;
  if (t == 0) { A = We0; B = We1; stride = 64; coff = c; }
  else if (t == 1 || t == 3) {
    int l = (t == 3);
    A = We_ss + l * 1024; B = We_sv + l * 1024; stride = 64; coff = c;
  } else {
    int l = (t == 4);
    stride = 32; coff = c & 31;
    if (c < 32) { A = We_vs + l * 512; B = We_vv + l * 512; }
    else        { A = We_vx + l * 512; B = nullptr; hasB = false; }
  }
  float ba = 0, bb = 0, a0 = 0, a1 = 0, b0 = 0, b1 = 0;
#pragma unroll
  for (int k = 0; k < 8; ++k) {
    float bt = bond_tab[v * 8 + k];
    float av_lo = A[k * stride + coff], av_hi = A[(8 + k) * stride + coff];
    ba += bt * av_lo;
    a0 += rb0[k] * av_hi; a1 += rb1[k] * av_hi;
    if (hasB) {
      float bv_lo = B[k * stride + coff], bv_hi = B[(8 + k) * stride + coff];
      bb += bt * bv_lo;
      b0 += rb0[k] * bv_hi; b1 += rb1[k] * bv_hi;
    }
  }
  float* o = tabs + (size_t)t * TBL_ELEMS + (((size_t)v * BINS + q) << 8) + c * 4;
  o[0] = ba + a0; o[1] = a1 - a0; o[2] = bb + b0; o[3] = b1 - b0;
}

// ---------------- embedding ----------------
__global__ void k_embed(const float* __restrict__ atom_tab, const int* __restrict__ types,
                        const float* __restrict__ ns0_w, const float* __restrict__ cnoise,
                        float* __restrict__ s_feat) {
  int tid = blockIdx.x * 256 + threadIdx.x;
  int n = tid >> 6, c = tid & 63;
  float cn = cnoise[0];
  s_feat[tid] = atom_tab[types[n] * 64 + c] * (1.f + cn * ns0_w[c]);
}

// ---------------- fused initial aggregation + init projections ----------------
// Output: sh [n][64], vh [n][32][4]
__global__ __launch_bounds__(256, 6) void k_agg0_fused(
    const int* __restrict__ offsets, const float* __restrict__ rec8,
    const float* __restrict__ T0, const float* __restrict__ s_feat,
    const float* __restrict__ Ws0, const float* __restrict__ Wself0,
    const float* __restrict__ Wv0,
    float* __restrict__ sh, float* __restrict__ vh) {
  __shared__ float ls[4][64];
  __shared__ float4 lv[4][64];
  int lane = threadIdx.x & 63;
  int w = threadIdx.x >> 6;
  int n = blockIdx.x * 4 + w;
  float acc = 0, a0 = 0, a1 = 0, a2 = 0;
  int beg = __builtin_amdgcn_readfirstlane(offsets[n]);
  int end = __builtin_amdgcn_readfirstlane(offsets[n + 1]);
  if (beg < end) {
    const float* rp0 = rec8 + (size_t)beg * 8;
    float4 rA = *(const float4*)rp0;
    float2 rB = *(const float2*)(rp0 + 4);
    int i1 = beg + (beg + 1 < end ? 1 : 0);
    const float* rp1 = rec8 + (size_t)i1 * 8;
    float4 nA = *(const float4*)rp1;
    float2 nB = *(const float2*)(rp1 + 4);
    float4 t4 = *(const float4*)(T0 + __float_as_int(rB.y) + (lane << 2));
    float sv = s_feat[((size_t)__float_as_int(rA.x) << 6) + lane];
#pragma unroll 2
    for (int idx = beg; idx < end; ++idx) {
      float4 pt4 = *(const float4*)(T0 + __float_as_int(nB.y) + (lane << 2));
      float psv = s_feat[((size_t)__float_as_int(nA.x) << 6) + lane];
      int i2 = (idx + 2 < end) ? idx + 2 : end - 1;
      const float* rp2 = rec8 + (size_t)i2 * 8;
      float4 fA = *(const float4*)rp2;
      float2 fB = *(const float2*)(rp2 + 4);
      float frac = rB.x;
      float w0 = fmaf(frac, t4.y, t4.x);
      float w1 = fmaf(frac, t4.w, t4.z);
      acc += w0 * sv;
      float t = w1 * sv;
      a0 += t * rA.y; a1 += t * rA.z; a2 += t * rA.w;
      rA = nA; rB = nB; nA = fA; nB = fB; t4 = pt4; sv = psv;
    }
  }
  ls[w][lane] = acc * INV_NORM;
  lv[w][lane] = make_float4(a0 * INV_NORM, a1 * INV_NORM, a2 * INV_NORM, 0.f);
  __syncthreads();
  // ---- epilogue: sh = a_s@Ws0 + s_feat@Wself0 ----
  {
    int d = lane;
    const float* lsw = ls[w];
    const float* sf = s_feat + ((size_t)n << 6);
    float s0 = 0, s1 = 0;
    for (int c = 0; c < 64; ++c) {
      s0 += lsw[c] * Ws0[c * 64 + d];
      s1 += sf[c] * Wself0[c * 64 + d];
    }
    sh[((size_t)n << 6) + d] = s0 + s1;
  }
  // ---- epilogue: vh = a_v@Wv0 (lanes 0-31) ----
  if (lane < 32) {
    int d = lane;
    float v0 = 0, v1 = 0, v2 = 0;
    for (int c = 0; c < 64; ++c) {
      float4 a = lv[w][c];
      float ww = Wv0[c * 32 + d];
      v0 += a.x * ww; v1 += a.y * ww; v2 += a.z * ww;
    }
    *(float4*)(vh + ((size_t)n << 7) + (d << 2)) = make_float4(v0, v1, v2, 0.f);
  }
}

// ---------------- fused layer aggregation + mix/self/skip ----------------
__global__ __launch_bounds__(256, 6) void k_agg_layer_fused(
    const float* __restrict__ cnoise, const float* __restrict__ nsw,
    const int* __restrict__ offsets, const float* __restrict__ rec8,
    const float* __restrict__ TS, const float* __restrict__ TU,
    const float* __restrict__ sh_in, const float* __restrict__ vh_in,
    const float* __restrict__ Wmix_s, const float* __restrict__ Wself_s,
    const float* __restrict__ Wmix_v, const float* __restrict__ Wself_v,
    const float* __restrict__ skw, const float* __restrict__ skb,
    float* __restrict__ sh_out, float* __restrict__ vh_out) {
  __shared__ float ls[4][96];
  __shared__ float4 lv[4][128];
  int lane = threadIdx.x & 63;
  int w = threadIdx.x >> 6;
  int n = blockIdx.x * 4 + w;
  int vc = lane & 31;
  bool low = lane < 32;
  float cn = cnoise[0];
  float scale_s = 1.f + cn * nsw[lane];
  float scale_v = 1.f + cn * nsw[64 + vc];

  float ms = 0;
  float av0 = 0, av1 = 0, av2 = 0;
  float ms2 = 0;
  float b0 = 0, b1 = 0, b2 = 0;
  int beg = __builtin_amdgcn_readfirstlane(offsets[n]);
  int end = __builtin_amdgcn_readfirstlane(offsets[n + 1]);
  if (beg < end) {
    const float* rp0 = rec8 + (size_t)beg * 8;
    float4 rA = *(const float4*)rp0;
    float2 rB = *(const float2*)(rp0 + 4);
    int i1 = beg + (beg + 1 < end ? 1 : 0);
    const float* rp1 = rec8 + (size_t)i1 * 8;
    float4 nA = *(const float4*)rp1;
    float2 nB = *(const float2*)(rp1 + 4);
    int src0 = __float_as_int(rA.x);
    int qo0 = __float_as_int(rB.y);
    float4 s4 = *(const float4*)(TS + qo0 + (lane << 2));
    float4 u4 = *(const float4*)(TU + qo0 + (lane << 2));
    float ss = sh_in[((size_t)src0 << 6) + lane];
    float4 v4 = *(const float4*)(vh_in + ((size_t)src0 << 7) + (vc << 2));
#pragma unroll 2
    for (int idx = beg; idx < end; ++idx) {
      int nsrc = __float_as_int(nA.x);
      int nqo = __float_as_int(nB.y);
      float4 ps4 = *(const float4*)(TS + nqo + (lane << 2));
      float4 pu4 = *(const float4*)(TU + nqo + (lane << 2));
      float pss = sh_in[((size_t)nsrc << 6) + lane];
      float4 pv4 = *(const float4*)(vh_in + ((size_t)nsrc << 7) + (vc << 2));
      int i2 = (idx + 2 < end) ? idx + 2 : end - 1;
      const float* rp2 = rec8 + (size_t)i2 * 8;
      float4 fA = *(const float4*)rp2;
      float2 fB = *(const float2*)(rp2 + 4);
      float frac = rB.x;
      float y0 = rA.y, y1 = rA.z, y2 = rA.w;
      float wS  = fmaf(frac, s4.y, s4.x);
      float wSV = fmaf(frac, s4.w, s4.z);
      float wA  = fmaf(frac, u4.y, u4.x);
      float wB  = fmaf(frac, u4.w, u4.z);
      float v0 = v4.x, v1 = v4.y, v2 = v4.z;
      ms += wS * ss;
      float t = wSV * ss;
      av0 += t * y0; av1 += t * y1; av2 += t * y2;
      float vdot = v0 * y0 + v1 * y1 + v2 * y2;
      ms2 += wA * vdot;  // garbage on high lanes, never written
      float cx = v1 * y2 - v2 * y1;
      float cy = v2 * y0 - v0 * y2;
      float cz = v0 * y1 - v1 * y0;
      float m0 = low ? v0 : cx;
      float m1 = low ? v1 : cy;
      float m2 = low ? v2 : cz;
      float wM = low ? wB : wA;
      b0 += wM * m0; b1 += wM * m1; b2 += wM * m2;
      rA = nA; rB = nB; nA = fA; nB = fB;
      s4 = ps4; u4 = pu4; ss = pss; v4 = pv4;
    }
  }
  float fs = scale_s * INV_NORM;
  float fv = scale_v * INV_NORM;
  ls[w][lane] = ms * fs;
  lv[w][lane] = make_float4(av0 * fs, av1 * fs, av2 * fs, 0.f);
  if (low) {
    ls[w][64 + vc] = ms2 * fv;
    lv[w][64 + vc] = make_float4(b0 * fv, b1 * fv, b2 * fv, 0.f);
  } else {
    lv[w][96 + vc] = make_float4(b0 * fv, b1 * fv, b2 * fv, 0.f);
  }
  __syncthreads();
  // ---- epilogue: new_s = a_s@Wmix_s + ss@Wself_s, gated skip ----
  {
    int d = lane;
    const float* lsw = ls[w];
    const float* shrow = sh_in + ((size_t)n << 6);
    float s0 = 0, s1 = 0;
    for (int c = 0; c < 96; ++c) s0 += lsw[c] * Wmix_s[c * 64 + d];
    for (int c = 0; c < 64; ++c)
      s1 += shrow[c] * (1.f + cn * nsw[c]) * Wself_s[c * 64 + d];
    float g1 = sigmoidf_(skb[d] + cn * skw[d]);
    float g2 = sigmoidf_(skb[64 + d] + cn * skw[64 + d]);
    sh_out[((size_t)n << 6) + d] = g1 * shrow[d] + g2 * (s0 + s1);
  }
  // ---- epilogue: new_v = a_v@Wmix_v + vv@Wself_v, gated skip (lanes 0-31) ----
  if (low) {
    int d = vc;
    float v0 = 0, v1 = 0, v2 = 0;
    for (int c = 0; c < 128; ++c) {
      float4 a = lv[w][c];
      float ww = Wmix_v[c * 32 + d];
      v0 += a.x * ww; v1 += a.y * ww; v2 += a.z * ww;
    }
    const float4* vrow = (const float4*)(vh_in + ((size_t)n << 7));
    for (int c = 0; c < 32; ++c) {
      float4 vv = vrow[c];
      float ww = Wself_v[c * 32 + d] * (1.f + cn * nsw[64 + c]);
      v0 += vv.x * ww; v1 += vv.y * ww; v2 += vv.z * ww;
    }
    float g3 = sigmoidf_(skb[128 + d] + cn * skw[128 + d]);
    float g4 = sigmoidf_(skb[160 + d] + cn * skw[160 + d]);
    float4 vi = vrow[d];
    *(float4*)(vh_out + ((size_t)n << 7) + (d << 2)) =
        make_float4(g3 * vi.x + g4 * v0, g3 * vi.y + g4 * v1, g3 * vi.z + g4 * v2, 0.f);
  }
}

// ---------------- output ----------------
__global__ void k_out(const float* __restrict__ vh, const float* __restrict__ w_out,
                      const float* __restrict__ gain, float* __restrict__ out) {
  int tid = blockIdx.x * 256 + threadIdx.x;  // < NA*3
  int n = tid / 3, i = tid - n * 3;
  float acc = 0;
  for (int c = 0; c < 32; ++c) acc += vh[((size_t)n << 7) + c * 4 + i] * w_out[c];
  out[tid] = acc * gain[0];
}

extern "C" void kernel_launch(void* const* d_in, const int* in_sizes, int n_in,
                              void* d_out, int out_size, void* d_ws, size_t ws_size,
                              hipStream_t stream) {
  (void)in_sizes; (void)n_in; (void)out_size; (void)ws_size;
  const float* pos     = (const float*)d_in[0];
  const float* cn      = (const float*)d_in[1];
  const int*   types   = (const int*)d_in[2];
  const int*   rad     = (const int*)d_in[3];
  const int*   bon     = (const int*)d_in[4];
  const float* atom_tab= (const float*)d_in[5];
  const float* bond_tab= (const float*)d_in[6];
  const float* ns0_w   = (const float*)d_in[7];
  const float* We0     = (const float*)d_in[8];
  const float* We1     = (const float*)d_in[9];
  const float* Wself0  = (const float*)d_in[10];
  const float* Ws0     = (const float*)d_in[11];
  const float* Wv0     = (const float*)d_in[12];
  const float* ns_w    = (const float*)d_in[13];
  const float* We_ss   = (const float*)d_in[14];
  const float* We_vs   = (const float*)d_in[15];
  const float* We_sv   = (const float*)d_in[16];
  const float* We_vv   = (const float*)d_in[17];
  const float* We_vx   = (const float*)d_in[18];
  const float* Wmix_s  = (const float*)d_in[19];
  const float* Wmix_v  = (const float*)d_in[20];
  const float* Wself_s = (const float*)d_in[21];
  const float* Wself_v = (const float*)d_in[22];
  const float* skip_w  = (const float*)d_in[23];
  const float* skip_b  = (const float*)d_in[24];
  const float* w_out   = (const float*)d_in[25];
  const float* gain    = (const float*)d_in[26];

  char* ws = (char*)d_ws;
  size_t o = 0;
  auto alloc = [&](size_t bytes) -> void* {
    void* p = ws + o;
    o += (bytes + 255) & ~(size_t)255;
    return p;
  };
  float* s_feat = (float*)alloc((size_t)NA * 64 * 4);
  float* sh0    = (float*)alloc((size_t)NA * 64 * 4);
  float* sh1    = (float*)alloc((size_t)NA * 64 * 4);
  float* vh0    = (float*)alloc((size_t)NA * 128 * 4);  // padded [n][32][4]
  float* vh1    = (float*)alloc((size_t)NA * 128 * 4);
  int* count    = (int*)alloc((size_t)NA * 4);
  int* offsets  = (int*)alloc((size_t)(NA + 1) * 4);
  int* sorted   = (int*)alloc((size_t)ET * 4);
  float* rec8   = (float*)alloc((size_t)ET * 32);
  float* tabs   = (float*)alloc((size_t)5 * TBL_ELEMS * 4);
  float* shb[2] = {sh0, sh1};
  float* vhb[2] = {vh0, vh1};

  // CSR build + tables
  k_zero<<<NA / 256, 256, 0, stream>>>(count);
  k_hist<<<ET / 256, 256, 0, stream>>>(rad, bon, count);
  k_scan<<<1, 256, 0, stream>>>(count, offsets);
  k_fill<<<ET / 256, 256, 0, stream>>>(rad, bon, count, sorted);
  k_edge_pre<<<ET / 256, 256, 0, stream>>>(pos, rad, bon, sorted, rec8);
  k_build<<<dim3(BINS, 5, 2), 64, 0, stream>>>(We0, We1, We_ss, We_vs, We_sv, We_vv, We_vx,
                                               bond_tab, tabs);

  k_embed<<<NA * 64 / 256, 256, 0, stream>>>(atom_tab, types, ns0_w, cn, s_feat);
  k_agg0_fused<<<NA / 4, 256, 0, stream>>>(offsets, rec8, tabs, s_feat,
                                           Ws0, Wself0, Wv0, shb[0], vhb[0]);

  for (int l = 0; l < 2; ++l) {
    int bin = l & 1, bout = 1 - bin;
    const float* TS = tabs + (size_t)(1 + 2 * l) * TBL_ELEMS;
    const float* TU = tabs + (size_t)(2 + 2 * l) * TBL_ELEMS;
    k_agg_layer_fused<<<NA / 4, 256, 0, stream>>>(
        cn, ns_w + l * 96, offsets, rec8, TS, TU, shb[bin], vhb[bin],
        Wmix_s + l * 96 * 64, Wself_s + l * 64 * 64,
        Wmix_v + l * 128 * 32, Wself_v + l * 32 * 32,
        skip_w + l * 192, skip_b + l * 192, shb[bout], vhb[bout]);
  }
  k_out<<<NA * 3 / 256, 256, 0, stream>>>(vhb[0], w_out, gain, (float*)d_out);
}

// Round 10
// 981.567 us; speedup vs baseline: 1.0662x; 1.0662x over previous
//
#include <hip/hip_runtime.h>
#include <math.h>

#define NA 16384
#define ER 524288
#define EB 32768
#define ET 557056
#define INV_NORM 0.17149858514250882f   // 1/sqrt((ER+EB)/NA) = 1/sqrt(34)
#define SQRT3 1.7320508075688772f
#define RB_STEP (1.5f/9.0f)
#define BINS 512
#define DMAX 2.5f
#define INV_H ((float)BINS / DMAX)
#define TBL_ELEMS (2 * BINS * 256)   // one table: [2][BINS][64][4] floats

__device__ __forceinline__ float sigmoidf_(float x) { return 1.f / (1.f + __expf(-x)); }

__device__ __forceinline__ int edge_dst(int e, const int* __restrict__ rad, const int* __restrict__ bon) {
  return (e < ER) ? rad[ER + e] : bon[EB + (e - ER)];
}

// ---------------- CSR build ----------------
__global__ void k_zero(int* __restrict__ count) {
  count[blockIdx.x * 256 + threadIdx.x] = 0;
}

__global__ void k_hist(const int* __restrict__ rad, const int* __restrict__ bon, int* __restrict__ count) {
  int e = blockIdx.x * 256 + threadIdx.x;
  atomicAdd(&count[edge_dst(e, rad, bon)], 1);
}

__global__ void k_scan(int* __restrict__ count, int* __restrict__ offsets) {
  __shared__ int part[256];
  int t = threadIdx.x;
  int base = t * 64;
  int s = 0;
  for (int j = 0; j < 64; ++j) s += count[base + j];
  part[t] = s;
  __syncthreads();
  for (int off = 1; off < 256; off <<= 1) {
    int v = (t >= off) ? part[t - off] : 0;
    __syncthreads();
    part[t] += v;
    __syncthreads();
  }
  int run = part[t] - s;  // exclusive prefix
  for (int j = 0; j < 64; ++j) {
    int c = count[base + j];
    offsets[base + j] = run;
    count[base + j] = run;  // becomes cursor for k_fill
    run += c;
  }
  if (t == 255) offsets[NA] = run;
}

__global__ void k_fill(const int* __restrict__ rad, const int* __restrict__ bon,
                       int* __restrict__ cursor, int* __restrict__ sorted) {
  int e = blockIdx.x * 256 + threadIdx.x;
  int d = edge_dst(e, rad, bon);
  int slot = atomicAdd(&cursor[d], 1);
  sorted[slot] = e;
}

// ---------------- per-edge record precompute ----------------
// record[idx] (32B): {src, Y0, Y1, Y2, frac, qoff(elem offset into a table), pad, pad}
__global__ void k_edge_pre(const float* __restrict__ pos,
                           const int* __restrict__ rad, const int* __restrict__ bon,
                           const int* __restrict__ sorted, float* __restrict__ rec8) {
  int idx = blockIdx.x * 256 + threadIdx.x;
  int e = sorted[idx];
  int src, dst, v;
  if (e < ER) { src = rad[e]; dst = rad[ER + e]; v = 0; }
  else        { src = bon[e - ER]; dst = bon[EB + e - ER]; v = 1; }
  float dx = pos[src * 3] - pos[dst * 3];
  float dy = pos[src * 3 + 1] - pos[dst * 3 + 1];
  float dz = pos[src * 3 + 2] - pos[dst * 3 + 2];
  float dist = sqrtf(dx * dx + dy * dy + dz * dz + 1e-12f);
  float inv = 1.f / dist;
  float fq = fminf(dist * INV_H, BINS - 1.001f);
  int q = (int)fq;
  float frac = fq - (float)q;
  int qoff = (v * BINS + q) << 8;   // 256 floats per row
  float* rp = rec8 + (size_t)idx * 8;
  *(float4*)rp = make_float4(__int_as_float(src), SQRT3 * dx * inv, SQRT3 * dy * inv, SQRT3 * dz * inv);
  rp[4] = frac;
  rp[5] = __int_as_float(qoff);
}

// ---------------- radial-weight tables with bond base folded ----------------
__global__ void k_build(const float* __restrict__ We0, const float* __restrict__ We1,
                        const float* __restrict__ We_ss, const float* __restrict__ We_vs,
                        const float* __restrict__ We_sv, const float* __restrict__ We_vv,
                        const float* __restrict__ We_vx, const float* __restrict__ bond_tab,
                        float* __restrict__ tabs) {
  int q = blockIdx.x, t = blockIdx.y, v = blockIdx.z, c = threadIdx.x;
  float d0 = q * (DMAX / BINS), d1 = (q + 1) * (DMAX / BINS);
  float rb0[8], rb1[8];
#pragma unroll
  for (int k = 0; k < 8; ++k) {
    float f0 = (d0 - (k + 1) * RB_STEP) * (1.f / RB_STEP);
    float f1 = (d1 - (k + 1) * RB_STEP) * (1.f / RB_STEP);
    rb0[k] = 1.12f * __expf(-f0 * f0);
    rb1[k] = 1.12f * __expf(-f1 * f1);
  }
  const float* A;
  const float* B;
  int stride, coff;
  bool hasB = true;
  if (t == 0) { A = We0; B = We1; stride = 64; coff = c; }
  else if (t == 1 || t == 3) {
    int l = (t == 3);
    A = We_ss + l * 1024; B = We_sv + l * 1024; stride = 64; coff = c;
  } else {
    int l = (t == 4);
    stride = 32; coff = c & 31;
    if (c < 32) { A = We_vs + l * 512; B = We_vv + l * 512; }
    else        { A = We_vx + l * 512; B = nullptr; hasB = false; }
  }
  float ba = 0, bb = 0, a0 = 0, a1 = 0, b0 = 0, b1 = 0;
#pragma unroll
  for (int k = 0; k < 8; ++k) {
    float bt = bond_tab[v * 8 + k];
    float av_lo = A[k * stride + coff], av_hi = A[(8 + k) * stride + coff];
    ba += bt * av_lo;
    a0 += rb0[k] * av_hi; a1 += rb1[k] * av_hi;
    if (hasB) {
      float bv_lo = B[k * stride + coff], bv_hi = B[(8 + k) * stride + coff];
      bb += bt * bv_lo;
      b0 += rb0[k] * bv_hi; b1 += rb1[k] * bv_hi;
    }
  }
  float* o = tabs + (size_t)t * TBL_ELEMS + (((size_t)v * BINS + q) << 8) + c * 4;
  o[0] = ba + a0; o[1] = a1 - a0; o[2] = bb + b0; o[3] = b1 - b0;
}

// ---------------- embedding ----------------
__global__ void k_embed(const float* __restrict__ atom_tab, const int* __restrict__ types,
                        const float* __restrict__ ns0_w, const float* __restrict__ cnoise,
                        float* __restrict__ s_feat) {
  int tid = blockIdx.x * 256 + threadIdx.x;
  int n = tid >> 6, c = tid & 63;
  float cn = cnoise[0];
  s_feat[tid] = atom_tab[types[n] * 64 + c] * (1.f + cn * ns0_w[c]);
}

// ---------------- fused initial aggregation + init projections ----------------
// Output: sh [n][64], vh [n][32][4]
__global__ __launch_bounds__(256, 4) void k_agg0_fused(
    const int* __restrict__ offsets, const float* __restrict__ rec8,
    const float* __restrict__ T0, const float* __restrict__ s_feat,
    const float* __restrict__ Ws0, const float* __restrict__ Wself0,
    const float* __restrict__ Wv0,
    float* __restrict__ sh, float* __restrict__ vh) {
  __shared__ float ls[4][64];
  __shared__ float4 lv[4][64];
  int lane = threadIdx.x & 63;
  int w = threadIdx.x >> 6;
  int n = blockIdx.x * 4 + w;
  float acc = 0, a0 = 0, a1 = 0, a2 = 0;
  int beg = __builtin_amdgcn_readfirstlane(offsets[n]);
  int end = __builtin_amdgcn_readfirstlane(offsets[n + 1]);
  if (beg < end) {
    const float* rp0 = rec8 + (size_t)beg * 8;
    float4 rA = *(const float4*)rp0;
    float2 rB = *(const float2*)(rp0 + 4);
    int i1 = beg + (beg + 1 < end ? 1 : 0);
    const float* rp1 = rec8 + (size_t)i1 * 8;
    float4 nA = *(const float4*)rp1;
    float2 nB = *(const float2*)(rp1 + 4);
    float4 t4 = *(const float4*)(T0 + __float_as_int(rB.y) + (lane << 2));
    float sv = s_feat[((size_t)__float_as_int(rA.x) << 6) + lane];
#pragma unroll 2
    for (int idx = beg; idx < end; ++idx) {
      float4 pt4 = *(const float4*)(T0 + __float_as_int(nB.y) + (lane << 2));
      float psv = s_feat[((size_t)__float_as_int(nA.x) << 6) + lane];
      int i2 = (idx + 2 < end) ? idx + 2 : end - 1;
      const float* rp2 = rec8 + (size_t)i2 * 8;
      float4 fA = *(const float4*)rp2;
      float2 fB = *(const float2*)(rp2 + 4);
      float frac = rB.x;
      float w0 = fmaf(frac, t4.y, t4.x);
      float w1 = fmaf(frac, t4.w, t4.z);
      acc += w0 * sv;
      float t = w1 * sv;
      a0 += t * rA.y; a1 += t * rA.z; a2 += t * rA.w;
      rA = nA; rB = nB; nA = fA; nB = fB; t4 = pt4; sv = psv;
    }
  }
  ls[w][lane] = acc * INV_NORM;
  lv[w][lane] = make_float4(a0 * INV_NORM, a1 * INV_NORM, a2 * INV_NORM, 0.f);
  __syncthreads();
  // ---- epilogue: sh = a_s@Ws0 + s_feat@Wself0 ----
  {
    int d = lane;
    const float* lsw = ls[w];
    const float* sf = s_feat + ((size_t)n << 6);
    float s0 = 0, s1 = 0;
    for (int c = 0; c < 64; ++c) {
      s0 += lsw[c] * Ws0[c * 64 + d];
      s1 += sf[c] * Wself0[c * 64 + d];
    }
    sh[((size_t)n << 6) + d] = s0 + s1;
  }
  // ---- epilogue: vh = a_v@Wv0 (lanes 0-31) ----
  if (lane < 32) {
    int d = lane;
    float v0 = 0, v1 = 0, v2 = 0;
    for (int c = 0; c < 64; ++c) {
      float4 a = lv[w][c];
      float ww = Wv0[c * 32 + d];
      v0 += a.x * ww; v1 += a.y * ww; v2 += a.z * ww;
    }
    *(float4*)(vh + ((size_t)n << 7) + (d << 2)) = make_float4(v0, v1, v2, 0.f);
  }
}

// ---------------- fused layer aggregation + mix/self/skip ----------------
__global__ __launch_bounds__(256, 4) void k_agg_layer_fused(
    const float* __restrict__ cnoise, const float* __restrict__ nsw,
    const int* __restrict__ offsets, const float* __restrict__ rec8,
    const float* __restrict__ TS, const float* __restrict__ TU,
    const float* __restrict__ sh_in, const float* __restrict__ vh_in,
    const float* __restrict__ Wmix_s, const float* __restrict__ Wself_s,
    const float* __restrict__ Wmix_v, const float* __restrict__ Wself_v,
    const float* __restrict__ skw, const float* __restrict__ skb,
    float* __restrict__ sh_out, float* __restrict__ vh_out) {
  __shared__ float ls[4][96];
  __shared__ float4 lv[4][128];
  int lane = threadIdx.x & 63;
  int w = threadIdx.x >> 6;
  int n = blockIdx.x * 4 + w;
  int vc = lane & 31;
  bool low = lane < 32;
  float cn = cnoise[0];
  float scale_s = 1.f + cn * nsw[lane];
  float scale_v = 1.f + cn * nsw[64 + vc];

  float ms = 0;
  float av0 = 0, av1 = 0, av2 = 0;
  float ms2 = 0;
  float b0 = 0, b1 = 0, b2 = 0;
  int beg = __builtin_amdgcn_readfirstlane(offsets[n]);
  int end = __builtin_amdgcn_readfirstlane(offsets[n + 1]);
  if (beg < end) {
    const float* rp0 = rec8 + (size_t)beg * 8;
    float4 rA = *(const float4*)rp0;
    float2 rB = *(const float2*)(rp0 + 4);
    int i1 = beg + (beg + 1 < end ? 1 : 0);
    const float* rp1 = rec8 + (size_t)i1 * 8;
    float4 nA = *(const float4*)rp1;
    float2 nB = *(const float2*)(rp1 + 4);
    int src0 = __float_as_int(rA.x);
    int qo0 = __float_as_int(rB.y);
    float4 s4 = *(const float4*)(TS + qo0 + (lane << 2));
    float4 u4 = *(const float4*)(TU + qo0 + (lane << 2));
    float ss = sh_in[((size_t)src0 << 6) + lane];
    float4 v4 = *(const float4*)(vh_in + ((size_t)src0 << 7) + (vc << 2));
#pragma unroll 2
    for (int idx = beg; idx < end; ++idx) {
      int nsrc = __float_as_int(nA.x);
      int nqo = __float_as_int(nB.y);
      float4 ps4 = *(const float4*)(TS + nqo + (lane << 2));
      float4 pu4 = *(const float4*)(TU + nqo + (lane << 2));
      float pss = sh_in[((size_t)nsrc << 6) + lane];
      float4 pv4 = *(const float4*)(vh_in + ((size_t)nsrc << 7) + (vc << 2));
      int i2 = (idx + 2 < end) ? idx + 2 : end - 1;
      const float* rp2 = rec8 + (size_t)i2 * 8;
      float4 fA = *(const float4*)rp2;
      float2 fB = *(const float2*)(rp2 + 4);
      float frac = rB.x;
      float y0 = rA.y, y1 = rA.z, y2 = rA.w;
      float wS  = fmaf(frac, s4.y, s4.x);
      float wSV = fmaf(frac, s4.w, s4.z);
      float wA  = fmaf(frac, u4.y, u4.x);
      float wB  = fmaf(frac, u4.w, u4.z);
      float v0 = v4.x, v1 = v4.y, v2 = v4.z;
      ms += wS * ss;
      float t = wSV * ss;
      av0 += t * y0; av1 += t * y1; av2 += t * y2;
      float vdot = v0 * y0 + v1 * y1 + v2 * y2;
      ms2 += wA * vdot;  // garbage on high lanes, never written
      float cx = v1 * y2 - v2 * y1;
      float cy = v2 * y0 - v0 * y2;
      float cz = v0 * y1 - v1 * y0;
      float m0 = low ? v0 : cx;
      float m1 = low ? v1 : cy;
      float m2 = low ? v2 : cz;
      float wM = low ? wB : wA;
      b0 += wM * m0; b1 += wM * m1; b2 += wM * m2;
      rA = nA; rB = nB; nA = fA; nB = fB;
      s4 = ps4; u4 = pu4; ss = pss; v4 = pv4;
    }
  }
  float fs = scale_s * INV_NORM;
  float fv = scale_v * INV_NORM;
  ls[w][lane] = ms * fs;
  lv[w][lane] = make_float4(av0 * fs, av1 * fs, av2 * fs, 0.f);
  if (low) {
    ls[w][64 + vc] = ms2 * fv;
    lv[w][64 + vc] = make_float4(b0 * fv, b1 * fv, b2 * fv, 0.f);
  } else {
    lv[w][96 + vc] = make_float4(b0 * fv, b1 * fv, b2 * fv, 0.f);
  }
  __syncthreads();
  // ---- epilogue: new_s = a_s@Wmix_s + ss@Wself_s, gated skip ----
  {
    int d = lane;
    const float* lsw = ls[w];
    const float* shrow = sh_in + ((size_t)n << 6);
    float s0 = 0, s1 = 0;
    for (int c = 0; c < 96; ++c) s0 += lsw[c] * Wmix_s[c * 64 + d];
    for (int c = 0; c < 64; ++c)
      s1 += shrow[c] * (1.f + cn * nsw[c]) * Wself_s[c * 64 + d];
    float g1 = sigmoidf_(skb[d] + cn * skw[d]);
    float g2 = sigmoidf_(skb[64 + d] + cn * skw[64 + d]);
    sh_out[((size_t)n << 6) + d] = g1 * shrow[d] + g2 * (s0 + s1);
  }
  // ---- epilogue: new_v = a_v@Wmix_v + vv@Wself_v, gated skip (lanes 0-31) ----
  if (low) {
    int d = vc;
    float v0 = 0, v1 = 0, v2 = 0;
    for (int c = 0; c < 128; ++c) {
      float4 a = lv[w][c];
      float ww = Wmix_v[c * 32 + d];
      v0 += a.x * ww; v1 += a.y * ww; v2 += a.z * ww;
    }
    const float4* vrow = (const float4*)(vh_in + ((size_t)n << 7));
    for (int c = 0; c < 32; ++c) {
      float4 vv = vrow[c];
      float ww = Wself_v[c * 32 + d] * (1.f + cn * nsw[64 + c]);
      v0 += vv.x * ww; v1 += vv.y * ww; v2 += vv.z * ww;
    }
    float g3 = sigmoidf_(skb[128 + d] + cn * skw[128 + d]);
    float g4 = sigmoidf_(skb[160 + d] + cn * skw[160 + d]);
    float4 vi = vrow[d];
    *(float4*)(vh_out + ((size_t)n << 7) + (d << 2)) =
        make_float4(g3 * vi.x + g4 * v0, g3 * vi.y + g4 * v1, g3 * vi.z + g4 * v2, 0.f);
  }
}

// ---------------- output ----------------
__global__ void k_out(const float* __restrict__ vh, const float* __restrict__ w_out,
                      const float* __restrict__ gain, float* __restrict__ out) {
  int tid = blockIdx.x * 256 + threadIdx.x;  // < NA*3
  int n = tid / 3, i = tid - n * 3;
  float acc = 0;
  for (int c = 0; c < 32; ++c) acc += vh[((size_t)n << 7) + c * 4 + i] * w_out[c];
  out[tid] = acc * gain[0];
}

extern "C" void kernel_launch(void* const* d_in, const int* in_sizes, int n_in,
                              void* d_out, int out_size, void* d_ws, size_t ws_size,
                              hipStream_t stream) {
  (void)in_sizes; (void)n_in; (void)out_size; (void)ws_size;
  const float* pos     = (const float*)d_in[0];
  const float* cn      = (const float*)d_in[1];
  const int*   types   = (const int*)d_in[2];
  const int*   rad     = (const int*)d_in[3];
  const int*   bon     = (const int*)d_in[4];
  const float* atom_tab= (const float*)d_in[5];
  const float* bond_tab= (const float*)d_in[6];
  const float* ns0_w   = (const float*)d_in[7];
  const float* We0     = (const float*)d_in[8];
  const float* We1     = (const float*)d_in[9];
  const float* Wself0  = (const float*)d_in[10];
  const float* Ws0     = (const float*)d_in[11];
  const float* Wv0     = (const float*)d_in[12];
  const float* ns_w    = (const float*)d_in[13];
  const float* We_ss   = (const float*)d_in[14];
  const float* We_vs   = (const float*)d_in[15];
  const float* We_sv   = (const float*)d_in[16];
  const float* We_vv   = (const float*)d_in[17];
  const float* We_vx   = (const float*)d_in[18];
  const float* Wmix_s  = (const float*)d_in[19];
  const float* Wmix_v  = (const float*)d_in[20];
  const float* Wself_s = (const float*)d_in[21];
  const float* Wself_v = (const float*)d_in[22];
  const float* skip_w  = (const float*)d_in[23];
  const float* skip_b  = (const float*)d_in[24];
  const float* w_out   = (const float*)d_in[25];
  const float* gain    = (const float*)d_in[26];

  char* ws = (char*)d_ws;
  size_t o = 0;
  auto alloc = [&](size_t bytes) -> void* {
    void* p = ws + o;
    o += (bytes + 255) & ~(size_t)255;
    return p;
  };
  float* s_feat = (float*)alloc((size_t)NA * 64 * 4);
  float* sh0    = (float*)alloc((size_t)NA * 64 * 4);
  float* sh1    = (float*)alloc((size_t)NA * 64 * 4);
  float* vh0    = (float*)alloc((size_t)NA * 128 * 4);  // padded [n][32][4]
  float* vh1    = (float*)alloc((size_t)NA * 128 * 4);
  int* count    = (int*)alloc((size_t)NA * 4);
  int* offsets  = (int*)alloc((size_t)(NA + 1) * 4);
  int* sorted   = (int*)alloc((size_t)ET * 4);
  float* rec8   = (float*)alloc((size_t)ET * 32);
  float* tabs   = (float*)alloc((size_t)5 * TBL_ELEMS * 4);
  float* shb[2] = {sh0, sh1};
  float* vhb[2] = {vh0, vh1};

  // CSR build + tables
  k_zero<<<NA / 256, 256, 0, stream>>>(count);
  k_hist<<<ET / 256, 256, 0, stream>>>(rad, bon, count);
  k_scan<<<1, 256, 0, stream>>>(count, offsets);
  k_fill<<<ET / 256, 256, 0, stream>>>(rad, bon, count, sorted);
  k_edge_pre<<<ET / 256, 256, 0, stream>>>(pos, rad, bon, sorted, rec8);
  k_build<<<dim3(BINS, 5, 2), 64, 0, stream>>>(We0, We1, We_ss, We_vs, We_sv, We_vv, We_vx,
                                               bond_tab, tabs);

  k_embed<<<NA * 64 / 256, 256, 0, stream>>>(atom_tab, types, ns0_w, cn, s_feat);
  k_agg0_fused<<<NA / 4, 256, 0, stream>>>(offsets, rec8, tabs, s_feat,
                                           Ws0, Wself0, Wv0, shb[0], vhb[0]);

  for (int l = 0; l < 2; ++l) {
    int bin = l & 1, bout = 1 - bin;
    const float* TS = tabs + (size_t)(1 + 2 * l) * TBL_ELEMS;
    const float* TU = tabs + (size_t)(2 + 2 * l) * TBL_ELEMS;
    k_agg_layer_fused<<<NA / 4, 256, 0, stream>>>(
        cn, ns_w + l * 96, offsets, rec8, TS, TU, shb[bin], vhb[bin],
        Wmix_s + l * 96 * 64, Wself_s + l * 64 * 64,
        Wmix_v + l * 128 * 32, Wself_v + l * 32 * 32,
        skip_w + l * 192, skip_b + l * 192, shb[bout], vhb[bout]);
  }
  k_out<<<NA * 3 / 256, 256, 0, stream>>>(vhb[0], w_out, gain, (float*)d_out);
}

// Round 11
// 537.003 us; speedup vs baseline: 1.9489x; 1.8279x over previous
//
#include <hip/hip_runtime.h>
#include <math.h>

#define NA 16384
#define ER 524288
#define EB 32768
#define ET 557056
#define INV_NORM 0.17149858514250882f   // 1/sqrt((ER+EB)/NA) = 1/sqrt(34)
#define SQRT3 1.7320508075688772f
#define RB_STEP (1.5f/9.0f)
#define BINS 512
#define DMAX 2.5f
#define INV_H ((float)BINS / DMAX)
#define TBL_ELEMS (2 * BINS * 256)   // one table: [2][BINS][64][4] floats

__device__ __forceinline__ float sigmoidf_(float x) { return 1.f / (1.f + __expf(-x)); }

__device__ __forceinline__ int edge_dst(int e, const int* __restrict__ rad, const int* __restrict__ bon) {
  return (e < ER) ? rad[ER + e] : bon[EB + (e - ER)];
}

// ---------------- CSR build ----------------
__global__ void k_zero(int* __restrict__ count) {
  count[blockIdx.x * 256 + threadIdx.x] = 0;
}

__global__ void k_hist(const int* __restrict__ rad, const int* __restrict__ bon, int* __restrict__ count) {
  int e = blockIdx.x * 256 + threadIdx.x;
  atomicAdd(&count[edge_dst(e, rad, bon)], 1);
}

__global__ void k_scan(int* __restrict__ count, int* __restrict__ offsets) {
  __shared__ int part[256];
  int t = threadIdx.x;
  int base = t * 64;
  int s = 0;
  for (int j = 0; j < 64; ++j) s += count[base + j];
  part[t] = s;
  __syncthreads();
  for (int off = 1; off < 256; off <<= 1) {
    int v = (t >= off) ? part[t - off] : 0;
    __syncthreads();
    part[t] += v;
    __syncthreads();
  }
  int run = part[t] - s;  // exclusive prefix
  for (int j = 0; j < 64; ++j) {
    int c = count[base + j];
    offsets[base + j] = run;
    count[base + j] = run;  // becomes cursor for k_fill
    run += c;
  }
  if (t == 255) offsets[NA] = run;
}

__global__ void k_fill(const int* __restrict__ rad, const int* __restrict__ bon,
                       int* __restrict__ cursor, int* __restrict__ sorted) {
  int e = blockIdx.x * 256 + threadIdx.x;
  int d = edge_dst(e, rad, bon);
  int slot = atomicAdd(&cursor[d], 1);
  sorted[slot] = e;
}

// ---------------- per-edge record precompute ----------------
// record[idx] (32B): {src, Y0, Y1, Y2, frac, qoff(elem offset into a table), pad, pad}
__global__ void k_edge_pre(const float* __restrict__ pos,
                           const int* __restrict__ rad, const int* __restrict__ bon,
                           const int* __restrict__ sorted, float* __restrict__ rec8) {
  int idx = blockIdx.x * 256 + threadIdx.x;
  int e = sorted[idx];
  int src, dst, v;
  if (e < ER) { src = rad[e]; dst = rad[ER + e]; v = 0; }
  else        { src = bon[e - ER]; dst = bon[EB + e - ER]; v = 1; }
  float dx = pos[src * 3] - pos[dst * 3];
  float dy = pos[src * 3 + 1] - pos[dst * 3 + 1];
  float dz = pos[src * 3 + 2] - pos[dst * 3 + 2];
  float dist = sqrtf(dx * dx + dy * dy + dz * dz + 1e-12f);
  float inv = 1.f / dist;
  float fq = fminf(dist * INV_H, BINS - 1.001f);
  int q = (int)fq;
  float frac = fq - (float)q;
  int qoff = (v * BINS + q) << 8;   // 256 floats per row
  float* rp = rec8 + (size_t)idx * 8;
  *(float4*)rp = make_float4(__int_as_float(src), SQRT3 * dx * inv, SQRT3 * dy * inv, SQRT3 * dz * inv);
  rp[4] = frac;
  rp[5] = __int_as_float(qoff);
}

// ---------------- radial-weight tables with bond base folded ----------------
__global__ void k_build(const float* __restrict__ We0, const float* __restrict__ We1,
                        const float* __restrict__ We_ss, const float* __restrict__ We_vs,
                        const float* __restrict__ We_sv, const float* __restrict__ We_vv,
                        const float* __restrict__ We_vx, const float* __restrict__ bond_tab,
                        float* __restrict__ tabs) {
  int q = blockIdx.x, t = blockIdx.y, v = blockIdx.z, c = threadIdx.x;
  float d0 = q * (DMAX / BINS), d1 = (q + 1) * (DMAX / BINS);
  float rb0[8], rb1[8];
#pragma unroll
  for (int k = 0; k < 8; ++k) {
    float f0 = (d0 - (k + 1) * RB_STEP) * (1.f / RB_STEP);
    float f1 = (d1 - (k + 1) * RB_STEP) * (1.f / RB_STEP);
    rb0[k] = 1.12f * __expf(-f0 * f0);
    rb1[k] = 1.12f * __expf(-f1 * f1);
  }
  const float* A;
  const float* B;
  int stride, coff;
  bool hasB = true;
  if (t == 0) { A = We0; B = We1; stride = 64; coff = c; }
  else if (t == 1 || t == 3) {
    int l = (t == 3);
    A = We_ss + l * 1024; B = We_sv + l * 1024; stride = 64; coff = c;
  } else {
    int l = (t == 4);
    stride = 32; coff = c & 31;
    if (c < 32) { A = We_vs + l * 512; B = We_vv + l * 512; }
    else        { A = We_vx + l * 512; B = nullptr; hasB = false; }
  }
  float ba = 0, bb = 0, a0 = 0, a1 = 0, b0 = 0, b1 = 0;
#pragma unroll
  for (int k = 0; k < 8; ++k) {
    float bt = bond_tab[v * 8 + k];
    float av_lo = A[k * stride + coff], av_hi = A[(8 + k) * stride + coff];
    ba += bt * av_lo;
    a0 += rb0[k] * av_hi; a1 += rb1[k] * av_hi;
    if (hasB) {
      float bv_lo = B[k * stride + coff], bv_hi = B[(8 + k) * stride + coff];
      bb += bt * bv_lo;
      b0 += rb0[k] * bv_hi; b1 += rb1[k] * bv_hi;
    }
  }
  float* o = tabs + (size_t)t * TBL_ELEMS + (((size_t)v * BINS + q) << 8) + c * 4;
  o[0] = ba + a0; o[1] = a1 - a0; o[2] = bb + b0; o[3] = b1 - b0;
}

// ---------------- embedding ----------------
__global__ void k_embed(const float* __restrict__ atom_tab, const int* __restrict__ types,
                        const float* __restrict__ ns0_w, const float* __restrict__ cnoise,
                        float* __restrict__ s_feat) {
  int tid = blockIdx.x * 256 + threadIdx.x;
  int n = tid >> 6, c = tid & 63;
  float cn = cnoise[0];
  s_feat[tid] = atom_tab[types[n] * 64 + c] * (1.f + cn * ns0_w[c]);
}

// ---------------- initial aggregation (R7 structure; a_v [n][64][4]) ----------------
__global__ __launch_bounds__(256, 6) void k_agg0(
    const int* __restrict__ offsets, const float* __restrict__ rec8,
    const float* __restrict__ T0, const float* __restrict__ s_feat,
    float* __restrict__ a_s, float* __restrict__ a_v) {
  int lane = threadIdx.x & 63;
  int n = blockIdx.x * 4 + (threadIdx.x >> 6);
  float acc = 0, a0 = 0, a1 = 0, a2 = 0;
  int beg = __builtin_amdgcn_readfirstlane(offsets[n]);
  int end = __builtin_amdgcn_readfirstlane(offsets[n + 1]);
  if (beg < end) {
    const float* rp0 = rec8 + (size_t)beg * 8;
    float4 rA = *(const float4*)rp0;
    float2 rB = *(const float2*)(rp0 + 4);
    int i1 = beg + (beg + 1 < end ? 1 : 0);
    const float* rp1 = rec8 + (size_t)i1 * 8;
    float4 nA = *(const float4*)rp1;
    float2 nB = *(const float2*)(rp1 + 4);
    float4 t4 = *(const float4*)(T0 + __float_as_int(rB.y) + (lane << 2));
    float sv = s_feat[((size_t)__float_as_int(rA.x) << 6) + lane];
#pragma unroll 2
    for (int idx = beg; idx < end; ++idx) {
      float4 pt4 = *(const float4*)(T0 + __float_as_int(nB.y) + (lane << 2));
      float psv = s_feat[((size_t)__float_as_int(nA.x) << 6) + lane];
      int i2 = (idx + 2 < end) ? idx + 2 : end - 1;
      const float* rp2 = rec8 + (size_t)i2 * 8;
      float4 fA = *(const float4*)rp2;
      float2 fB = *(const float2*)(rp2 + 4);
      float frac = rB.x;
      float w0 = fmaf(frac, t4.y, t4.x);
      float w1 = fmaf(frac, t4.w, t4.z);
      acc += w0 * sv;
      float t = w1 * sv;
      a0 += t * rA.y; a1 += t * rA.z; a2 += t * rA.w;
      rA = nA; rB = nB; nA = fA; nB = fB; t4 = pt4; sv = psv;
    }
  }
  a_s[n * 64 + lane] = acc * INV_NORM;
  *(float4*)(a_v + ((size_t)n << 8) + (lane << 2)) =
      make_float4(a0 * INV_NORM, a1 * INV_NORM, a2 * INV_NORM, 0.f);
}

// ---------------- layer aggregation (R7 structure; a_v [n][128][4]) ----------------
__global__ __launch_bounds__(256, 6) void k_agg_layer(
    const float* __restrict__ cnoise, const float* __restrict__ nsw,
    const int* __restrict__ offsets, const float* __restrict__ rec8,
    const float* __restrict__ TS, const float* __restrict__ TU,
    const float* __restrict__ sh_in, const float* __restrict__ vh_in,
    float* __restrict__ a_s, float* __restrict__ a_v) {
  int lane = threadIdx.x & 63;
  int n = blockIdx.x * 4 + (threadIdx.x >> 6);
  int vc = lane & 31;
  bool low = lane < 32;
  float cn = cnoise[0];
  float scale_s = 1.f + cn * nsw[lane];
  float scale_v = 1.f + cn * nsw[64 + vc];

  float ms = 0;
  float av0 = 0, av1 = 0, av2 = 0;
  float ms2 = 0;
  float b0 = 0, b1 = 0, b2 = 0;
  int beg = __builtin_amdgcn_readfirstlane(offsets[n]);
  int end = __builtin_amdgcn_readfirstlane(offsets[n + 1]);
  if (beg < end) {
    const float* rp0 = rec8 + (size_t)beg * 8;
    float4 rA = *(const float4*)rp0;
    float2 rB = *(const float2*)(rp0 + 4);
    int i1 = beg + (beg + 1 < end ? 1 : 0);
    const float* rp1 = rec8 + (size_t)i1 * 8;
    float4 nA = *(const float4*)rp1;
    float2 nB = *(const float2*)(rp1 + 4);
    int src0 = __float_as_int(rA.x);
    int qo0 = __float_as_int(rB.y);
    float4 s4 = *(const float4*)(TS + qo0 + (lane << 2));
    float4 u4 = *(const float4*)(TU + qo0 + (lane << 2));
    float ss = sh_in[((size_t)src0 << 6) + lane];
    float4 v4 = *(const float4*)(vh_in + ((size_t)src0 << 7) + (vc << 2));
#pragma unroll 2
    for (int idx = beg; idx < end; ++idx) {
      int nsrc = __float_as_int(nA.x);
      int nqo = __float_as_int(nB.y);
      float4 ps4 = *(const float4*)(TS + nqo + (lane << 2));
      float4 pu4 = *(const float4*)(TU + nqo + (lane << 2));
      float pss = sh_in[((size_t)nsrc << 6) + lane];
      float4 pv4 = *(const float4*)(vh_in + ((size_t)nsrc << 7) + (vc << 2));
      int i2 = (idx + 2 < end) ? idx + 2 : end - 1;
      const float* rp2 = rec8 + (size_t)i2 * 8;
      float4 fA = *(const float4*)rp2;
      float2 fB = *(const float2*)(rp2 + 4);
      float frac = rB.x;
      float y0 = rA.y, y1 = rA.z, y2 = rA.w;
      float wS  = fmaf(frac, s4.y, s4.x);
      float wSV = fmaf(frac, s4.w, s4.z);
      float wA  = fmaf(frac, u4.y, u4.x);
      float wB  = fmaf(frac, u4.w, u4.z);
      float v0 = v4.x, v1 = v4.y, v2 = v4.z;
      ms += wS * ss;
      float t = wSV * ss;
      av0 += t * y0; av1 += t * y1; av2 += t * y2;
      float vdot = v0 * y0 + v1 * y1 + v2 * y2;
      ms2 += wA * vdot;  // garbage on high lanes, never written
      float cx = v1 * y2 - v2 * y1;
      float cy = v2 * y0 - v0 * y2;
      float cz = v0 * y1 - v1 * y0;
      float m0 = low ? v0 : cx;
      float m1 = low ? v1 : cy;
      float m2 = low ? v2 : cz;
      float wM = low ? wB : wA;
      b0 += wM * m0; b1 += wM * m1; b2 += wM * m2;
      rA = nA; rB = nB; nA = fA; nB = fB;
      s4 = ps4; u4 = pu4; ss = pss; v4 = pv4;
    }
  }
  float fs = scale_s * INV_NORM;
  float fv = scale_v * INV_NORM;
  a_s[n * 96 + lane] = ms * fs;
  float* avn = a_v + ((size_t)n << 9);
  *(float4*)(avn + (lane << 2)) = make_float4(av0 * fs, av1 * fs, av2 * fs, 0.f);
  if (low) {
    a_s[n * 96 + 64 + vc] = ms2 * fv;
    *(float4*)(avn + ((64 + vc) << 2)) = make_float4(b0 * fv, b1 * fv, b2 * fv, 0.f);
  } else {
    *(float4*)(avn + ((96 + vc) << 2)) = make_float4(b0 * fv, b1 * fv, b2 * fv, 0.f);
  }
}

// ---------------- init projections: LDS-staged matvecs ----------------
__global__ __launch_bounds__(256, 4) void k_init_s(
    const float* __restrict__ a_s, const float* __restrict__ s_feat,
    const float* __restrict__ Ws0, const float* __restrict__ Wself0,
    float* __restrict__ sh) {
  __shared__ float W1[64 * 64];
  __shared__ float W2[64 * 64];
  __shared__ float La[8 * 64];
  __shared__ float Lf[8 * 64];
  int tid = threadIdx.x;
  for (int i = tid; i < 1024; i += 256) {
    ((float4*)W1)[i] = ((const float4*)Ws0)[i];
    ((float4*)W2)[i] = ((const float4*)Wself0)[i];
  }
  int base = blockIdx.x * 8;
  for (int i = tid; i < 512; i += 256) {
    La[i] = a_s[(size_t)base * 64 + i];
    Lf[i] = s_feat[(size_t)base * 64 + i];
  }
  __syncthreads();
  int d = tid & 63, g = tid >> 6;
  int n0 = base + g * 2;
  const float* A0 = La + g * 128;
  const float* A1 = A0 + 64;
  const float* F0 = Lf + g * 128;
  const float* F1 = F0 + 64;
  float a0 = 0, a1 = 0;
#pragma unroll 8
  for (int c = 0; c < 64; ++c) {
    float w1 = W1[c * 64 + d], w2 = W2[c * 64 + d];
    a0 += A0[c] * w1 + F0[c] * w2;
    a1 += A1[c] * w1 + F1[c] * w2;
  }
  sh[(size_t)n0 * 64 + d] = a0;
  sh[(size_t)(n0 + 1) * 64 + d] = a1;
}

__global__ __launch_bounds__(256, 4) void k_init_v(
    const float* __restrict__ a_v, const float* __restrict__ Wv0,
    float* __restrict__ vh) {
  __shared__ float W[64 * 32];  // 8KB
  int tid = threadIdx.x;
  for (int i = tid; i < 512; i += 256) ((float4*)W)[i] = ((const float4*)Wv0)[i];
  __syncthreads();
  int d = tid & 31, g = tid >> 5;
  int n = blockIdx.x * 8 + g;
  const float4* av = (const float4*)(a_v + ((size_t)n << 8));
  float x = 0, y = 0, z = 0;
#pragma unroll 4
  for (int c = 0; c < 64; ++c) {
    float4 a = av[c];
    float w = W[c * 32 + d];
    x += a.x * w; y += a.y * w; z += a.z * w;
  }
  *(float4*)(vh + ((size_t)n << 7) + (d << 2)) = make_float4(x, y, z, 0.f);
}

// ---------------- mix/self/skip: LDS-staged matvecs ----------------
__global__ __launch_bounds__(256, 4) void k_mix_s(
    const float* __restrict__ a_s, const float* __restrict__ sh_in,
    const float* __restrict__ Wmix_s, const float* __restrict__ Wself_s,
    const float* __restrict__ nsw, const float* __restrict__ skw,
    const float* __restrict__ skb, const float* __restrict__ cnoise,
    float* __restrict__ sh_out) {
  __shared__ float Wm[96 * 64];   // 24KB
  __shared__ float Wsf[64 * 64];  // 16KB (scale folded in)
  __shared__ float La[8 * 96];    // 3KB
  int tid = threadIdx.x;
  float cn = cnoise[0];
  for (int i = tid; i < 96 * 16; i += 256) ((float4*)Wm)[i] = ((const float4*)Wmix_s)[i];
  for (int i = tid; i < 64 * 16; i += 256) {
    float4 wv = ((const float4*)Wself_s)[i];
    int c = i >> 4;
    float sc = 1.f + cn * nsw[c];
    wv.x *= sc; wv.y *= sc; wv.z *= sc; wv.w *= sc;
    ((float4*)Wsf)[i] = wv;
  }
  int base = blockIdx.x * 8;
  for (int i = tid; i < 8 * 96; i += 256) La[i] = a_s[(size_t)base * 96 + i];
  __syncthreads();
  int d = tid & 63, g = tid >> 6;
  int n0 = base + g * 2;
  const float* A0 = La + (g * 2) * 96;
  const float* A1 = A0 + 96;
  const float* s0p = sh_in + (size_t)n0 * 64;
  const float* s1p = s0p + 64;
  float acc0 = 0, acc1 = 0;
#pragma unroll 8
  for (int c = 0; c < 96; ++c) {
    float w = Wm[c * 64 + d];
    acc0 += A0[c] * w;
    acc1 += A1[c] * w;
  }
#pragma unroll 8
  for (int c = 0; c < 64; ++c) {
    float w = Wsf[c * 64 + d];
    acc0 += s0p[c] * w;
    acc1 += s1p[c] * w;
  }
  float g1 = sigmoidf_(skb[d] + cn * skw[d]);
  float g2 = sigmoidf_(skb[64 + d] + cn * skw[64 + d]);
  sh_out[(size_t)n0 * 64 + d] = g1 * s0p[d] + g2 * acc0;
  sh_out[(size_t)(n0 + 1) * 64 + d] = g1 * s1p[d] + g2 * acc1;
}

__global__ __launch_bounds__(256, 4) void k_mix_v(
    const float* __restrict__ a_v, const float* __restrict__ vh_in,
    const float* __restrict__ Wmix_v, const float* __restrict__ Wself_v,
    const float* __restrict__ nsw, const float* __restrict__ skw,
    const float* __restrict__ skb, const float* __restrict__ cnoise,
    float* __restrict__ vh_out) {
  __shared__ float Wm[128 * 32];   // 16KB
  __shared__ float Wsf[32 * 32];   // 4KB (scale folded in)
  int tid = threadIdx.x;
  float cn = cnoise[0];
  for (int i = tid; i < 128 * 8; i += 256) ((float4*)Wm)[i] = ((const float4*)Wmix_v)[i];
  for (int i = tid; i < 32 * 8; i += 256) {
    float4 wv = ((const float4*)Wself_v)[i];
    int c = i >> 3;
    float sc = 1.f + cn * nsw[64 + c];
    wv.x *= sc; wv.y *= sc; wv.z *= sc; wv.w *= sc;
    ((float4*)Wsf)[i] = wv;
  }
  __syncthreads();
  int d = tid & 31, g = tid >> 5;
  int n = blockIdx.x * 8 + g;
  const float4* av = (const float4*)(a_v + ((size_t)n << 9));
  const float4* vr = (const float4*)(vh_in + ((size_t)n << 7));
  float x = 0, y = 0, z = 0;
#pragma unroll 4
  for (int c = 0; c < 128; ++c) {
    float4 a = av[c];
    float w = Wm[c * 32 + d];
    x += a.x * w; y += a.y * w; z += a.z * w;
  }
#pragma unroll 4
  for (int c = 0; c < 32; ++c) {
    float4 vv = vr[c];
    float w = Wsf[c * 32 + d];
    x += vv.x * w; y += vv.y * w; z += vv.z * w;
  }
  float g3 = sigmoidf_(skb[128 + d] + cn * skw[128 + d]);
  float g4 = sigmoidf_(skb[160 + d] + cn * skw[160 + d]);
  float4 vi = vr[d];
  *(float4*)(vh_out + ((size_t)n << 7) + (d << 2)) =
      make_float4(g3 * vi.x + g4 * x, g3 * vi.y + g4 * y, g3 * vi.z + g4 * z, 0.f);
}

// ---------------- output ----------------
__global__ void k_out(const float* __restrict__ vh, const float* __restrict__ w_out,
                      const float* __restrict__ gain, float* __restrict__ out) {
  int tid = blockIdx.x * 256 + threadIdx.x;  // < NA*3
  int n = tid / 3, i = tid - n * 3;
  float acc = 0;
  for (int c = 0; c < 32; ++c) acc += vh[((size_t)n << 7) + c * 4 + i] * w_out[c];
  out[tid] = acc * gain[0];
}

extern "C" void kernel_launch(void* const* d_in, const int* in_sizes, int n_in,
                              void* d_out, int out_size, void* d_ws, size_t ws_size,
                              hipStream_t stream) {
  (void)in_sizes; (void)n_in; (void)out_size; (void)ws_size;
  const float* pos     = (const float*)d_in[0];
  const float* cn      = (const float*)d_in[1];
  const int*   types   = (const int*)d_in[2];
  const int*   rad     = (const int*)d_in[3];
  const int*   bon     = (const int*)d_in[4];
  const float* atom_tab= (const float*)d_in[5];
  const float* bond_tab= (const float*)d_in[6];
  const float* ns0_w   = (const float*)d_in[7];
  const float* We0     = (const float*)d_in[8];
  const float* We1     = (const float*)d_in[9];
  const float* Wself0  = (const float*)d_in[10];
  const float* Ws0     = (const float*)d_in[11];
  const float* Wv0     = (const float*)d_in[12];
  const float* ns_w    = (const float*)d_in[13];
  const float* We_ss   = (const float*)d_in[14];
  const float* We_vs   = (const float*)d_in[15];
  const float* We_sv   = (const float*)d_in[16];
  const float* We_vv   = (const float*)d_in[17];
  const float* We_vx   = (const float*)d_in[18];
  const float* Wmix_s  = (const float*)d_in[19];
  const float* Wmix_v  = (const float*)d_in[20];
  const float* Wself_s = (const float*)d_in[21];
  const float* Wself_v = (const float*)d_in[22];
  const float* skip_w  = (const float*)d_in[23];
  const float* skip_b  = (const float*)d_in[24];
  const float* w_out   = (const float*)d_in[25];
  const float* gain    = (const float*)d_in[26];

  char* ws = (char*)d_ws;
  size_t o = 0;
  auto alloc = [&](size_t bytes) -> void* {
    void* p = ws + o;
    o += (bytes + 255) & ~(size_t)255;
    return p;
  };
  float* s_feat = (float*)alloc((size_t)NA * 64 * 4);
  float* a_s    = (float*)alloc((size_t)NA * 96 * 4);
  float* a_v    = (float*)alloc((size_t)NA * 512 * 4);  // [n][128][4], agg0 uses [n][64][4]
  float* sh0    = (float*)alloc((size_t)NA * 64 * 4);
  float* sh1    = (float*)alloc((size_t)NA * 64 * 4);
  float* vh0    = (float*)alloc((size_t)NA * 128 * 4);  // padded [n][32][4]
  float* vh1    = (float*)alloc((size_t)NA * 128 * 4);
  int* count    = (int*)alloc((size_t)NA * 4);
  int* offsets  = (int*)alloc((size_t)(NA + 1) * 4);
  int* sorted   = (int*)alloc((size_t)ET * 4);
  float* rec8   = (float*)alloc((size_t)ET * 32);
  float* tabs   = (float*)alloc((size_t)5 * TBL_ELEMS * 4);
  float* shb[2] = {sh0, sh1};
  float* vhb[2] = {vh0, vh1};

  // CSR build + tables
  k_zero<<<NA / 256, 256, 0, stream>>>(count);
  k_hist<<<ET / 256, 256, 0, stream>>>(rad, bon, count);
  k_scan<<<1, 256, 0, stream>>>(count, offsets);
  k_fill<<<ET / 256, 256, 0, stream>>>(rad, bon, count, sorted);
  k_edge_pre<<<ET / 256, 256, 0, stream>>>(pos, rad, bon, sorted, rec8);
  k_build<<<dim3(BINS, 5, 2), 64, 0, stream>>>(We0, We1, We_ss, We_vs, We_sv, We_vv, We_vx,
                                               bond_tab, tabs);

  k_embed<<<NA * 64 / 256, 256, 0, stream>>>(atom_tab, types, ns0_w, cn, s_feat);
  k_agg0<<<NA / 4, 256, 0, stream>>>(offsets, rec8, tabs, s_feat, a_s, a_v);
  k_init_s<<<NA / 8, 256, 0, stream>>>(a_s, s_feat, Ws0, Wself0, shb[0]);
  k_init_v<<<NA / 8, 256, 0, stream>>>(a_v, Wv0, vhb[0]);

  for (int l = 0; l < 2; ++l) {
    int bin = l & 1, bout = 1 - bin;
    const float* TS = tabs + (size_t)(1 + 2 * l) * TBL_ELEMS;
    const float* TU = tabs + (size_t)(2 + 2 * l) * TBL_ELEMS;
    k_agg_layer<<<NA / 4, 256, 0, stream>>>(
        cn, ns_w + l * 96, offsets, rec8, TS, TU, shb[bin], vhb[bin], a_s, a_v);
    k_mix_s<<<NA / 8, 256, 0, stream>>>(
        a_s, shb[bin], Wmix_s + l * 96 * 64, Wself_s + l * 64 * 64,
        ns_w + l * 96, skip_w + l * 192, skip_b + l * 192, cn, shb[bout]);
    k_mix_v<<<NA / 8, 256, 0, stream>>>(
        a_v, vhb[bin], Wmix_v + l * 128 * 32, Wself_v + l * 32 * 32,
        ns_w + l * 96, skip_w + l * 192, skip_b + l * 192, cn, vhb[bout]);
  }
  k_out<<<NA * 3 / 256, 256, 0, stream>>>(vhb[0], w_out, gain, (float*)d_out);
}

// Round 12
// 526.807 us; speedup vs baseline: 1.9866x; 1.0194x over previous
//
#include <hip/hip_runtime.h>
#include <math.h>

#define NA 16384
#define ER 524288
#define EB 32768
#define ET 557056
#define INV_NORM 0.17149858514250882f   // 1/sqrt((ER+EB)/NA) = 1/sqrt(34)
#define SQRT3 1.7320508075688772f
#define RB_STEP (1.5f/9.0f)
#define BINS 512
#define DMAX 2.5f
#define INV_H ((float)BINS / DMAX)
#define TBLU (2 * BINS * 128)   // one bf16 table: [2][BINS][64][2] uints

typedef unsigned int uint32;
typedef unsigned short ushort16;

__device__ __forceinline__ float sigmoidf_(float x) { return 1.f / (1.f + __expf(-x)); }

__device__ __forceinline__ ushort16 f2bf(float x) {
  uint32 u = __float_as_uint(x);
  u = u + 0x7FFFu + ((u >> 16) & 1u);
  return (ushort16)(u >> 16);
}
__device__ __forceinline__ uint32 packbf(float hi, float lo) {
  return ((uint32)f2bf(hi) << 16) | (uint32)f2bf(lo);
}
__device__ __forceinline__ float bfhi(uint32 u) { return __uint_as_float(u & 0xFFFF0000u); }
__device__ __forceinline__ float bflo(uint32 u) { return __uint_as_float(u << 16); }

__device__ __forceinline__ int edge_dst(int e, const int* __restrict__ rad, const int* __restrict__ bon) {
  return (e < ER) ? rad[ER + e] : bon[EB + (e - ER)];
}

// ---------------- CSR build ----------------
__global__ void k_zero(int* __restrict__ count) {
  count[blockIdx.x * 256 + threadIdx.x] = 0;
}

__global__ void k_hist(const int* __restrict__ rad, const int* __restrict__ bon, int* __restrict__ count) {
  int e = blockIdx.x * 256 + threadIdx.x;
  atomicAdd(&count[edge_dst(e, rad, bon)], 1);
}

__global__ void k_scan1(const int* __restrict__ count, int* __restrict__ partial) {
  __shared__ int red[256];
  int b = blockIdx.x, t = threadIdx.x;
  red[t] = count[b * 256 + t];
  __syncthreads();
  for (int s = 128; s > 0; s >>= 1) {
    if (t < s) red[t] += red[t + s];
    __syncthreads();
  }
  if (t == 0) partial[b] = red[0];
}

__global__ void k_scan2(int* __restrict__ partial) {
  int run = 0;
  for (int i = 0; i < 64; ++i) { int c = partial[i]; partial[i] = run; run += c; }
}

__global__ void k_scan3(const int* __restrict__ count, const int* __restrict__ partial,
                        int* __restrict__ offsets, int* __restrict__ cursor) {
  __shared__ int sc[256];
  int b = blockIdx.x, t = threadIdx.x;
  int v = count[b * 256 + t];
  sc[t] = v;
  __syncthreads();
  for (int off = 1; off < 256; off <<= 1) {
    int x = (t >= off) ? sc[t - off] : 0;
    __syncthreads();
    sc[t] += x;
    __syncthreads();
  }
  int excl = sc[t] - v + partial[b];
  offsets[b * 256 + t] = excl;
  cursor[b * 256 + t] = excl;
  if (b == 63 && t == 255) offsets[NA] = excl + v;
}

__global__ void k_fill(const int* __restrict__ rad, const int* __restrict__ bon,
                       int* __restrict__ cursor, int* __restrict__ sorted) {
  int e = blockIdx.x * 256 + threadIdx.x;
  int d = edge_dst(e, rad, bon);
  int slot = atomicAdd(&cursor[d], 1);
  sorted[slot] = e;
}

// ---------------- per-edge record precompute ----------------
// record[idx] (32B): {src, Y0, Y1, Y2, frac, qoff(uint elems into a bf16 table), pad, pad}
__global__ void k_edge_pre(const float* __restrict__ pos,
                           const int* __restrict__ rad, const int* __restrict__ bon,
                           const int* __restrict__ sorted, float* __restrict__ rec8) {
  int idx = blockIdx.x * 256 + threadIdx.x;
  int e = sorted[idx];
  int src, dst, v;
  if (e < ER) { src = rad[e]; dst = rad[ER + e]; v = 0; }
  else        { src = bon[e - ER]; dst = bon[EB + e - ER]; v = 1; }
  float dx = pos[src * 3] - pos[dst * 3];
  float dy = pos[src * 3 + 1] - pos[dst * 3 + 1];
  float dz = pos[src * 3 + 2] - pos[dst * 3 + 2];
  float dist = sqrtf(dx * dx + dy * dy + dz * dz + 1e-12f);
  float inv = 1.f / dist;
  float fq = fminf(dist * INV_H, BINS - 1.001f);
  int q = (int)fq;
  float frac = fq - (float)q;
  int qoff = (v * BINS + q) << 7;   // 128 uints per row
  float* rp = rec8 + (size_t)idx * 8;
  *(float4*)rp = make_float4(__int_as_float(src), SQRT3 * dx * inv, SQRT3 * dy * inv, SQRT3 * dz * inv);
  rp[4] = frac;
  rp[5] = __int_as_float(qoff);
}

// ---------------- bf16 radial-weight tables with bond base folded ----------------
// 5 tables, each [variant(2)][BINS][64 lanes][2 uints]; uint = {bf16 w | bf16 dw}
//   t=0: agg0 {pair(w0), pair(w1)}
//   t=1/3: layer0/1 S {pair(w_ss), pair(w_sv)}
//   t=2/4: layer0/1 U: lane<32 {pair(w_vs), pair(w_vv)}; lane>=32 {pair(w_vx), 0}
__global__ void k_build(const float* __restrict__ We0, const float* __restrict__ We1,
                        const float* __restrict__ We_ss, const float* __restrict__ We_vs,
                        const float* __restrict__ We_sv, const float* __restrict__ We_vv,
                        const float* __restrict__ We_vx, const float* __restrict__ bond_tab,
                        uint32* __restrict__ tabs) {
  int q = blockIdx.x, t = blockIdx.y, v = blockIdx.z, c = threadIdx.x;
  float d0 = q * (DMAX / BINS), d1 = (q + 1) * (DMAX / BINS);
  float rb0[8], rb1[8];
#pragma unroll
  for (int k = 0; k < 8; ++k) {
    float f0 = (d0 - (k + 1) * RB_STEP) * (1.f / RB_STEP);
    float f1 = (d1 - (k + 1) * RB_STEP) * (1.f / RB_STEP);
    rb0[k] = 1.12f * __expf(-f0 * f0);
    rb1[k] = 1.12f * __expf(-f1 * f1);
  }
  const float* A;
  const float* B;
  int stride, coff;
  bool hasB = true;
  if (t == 0) { A = We0; B = We1; stride = 64; coff = c; }
  else if (t == 1 || t == 3) {
    int l = (t == 3);
    A = We_ss + l * 1024; B = We_sv + l * 1024; stride = 64; coff = c;
  } else {
    int l = (t == 4);
    stride = 32; coff = c & 31;
    if (c < 32) { A = We_vs + l * 512; B = We_vv + l * 512; }
    else        { A = We_vx + l * 512; B = nullptr; hasB = false; }
  }
  float ba = 0, bb = 0, a0 = 0, a1 = 0, b0 = 0, b1 = 0;
#pragma unroll
  for (int k = 0; k < 8; ++k) {
    float bt = bond_tab[v * 8 + k];
    float av_lo = A[k * stride + coff], av_hi = A[(8 + k) * stride + coff];
    ba += bt * av_lo;
    a0 += rb0[k] * av_hi; a1 += rb1[k] * av_hi;
    if (hasB) {
      float bv_lo = B[k * stride + coff], bv_hi = B[(8 + k) * stride + coff];
      bb += bt * bv_lo;
      b0 += rb0[k] * bv_hi; b1 += rb1[k] * bv_hi;
    }
  }
  uint32* o = tabs + (size_t)t * TBLU + (((size_t)v * BINS + q) << 7) + c * 2;
  o[0] = packbf(ba + a0, a1 - a0);
  o[1] = hasB ? packbf(bb + b0, b1 - b0) : 0u;
}

// ---------------- embedding (f32 + bf16 mirror) ----------------
__global__ void k_embed(const float* __restrict__ atom_tab, const int* __restrict__ types,
                        const float* __restrict__ ns0_w, const float* __restrict__ cnoise,
                        float* __restrict__ s_feat, ushort16* __restrict__ s_bf) {
  int tid = blockIdx.x * 256 + threadIdx.x;
  int n = tid >> 6, c = tid & 63;
  float cn = cnoise[0];
  float v = atom_tab[types[n] * 64 + c] * (1.f + cn * ns0_w[c]);
  s_feat[tid] = v;
  s_bf[tid] = f2bf(v);
}

// ---------------- initial aggregation (bf16 gathers; a_v [n][64][4]) ----------------
__global__ __launch_bounds__(256, 6) void k_agg0(
    const int* __restrict__ offsets, const float* __restrict__ rec8,
    const uint32* __restrict__ T0, const ushort16* __restrict__ s_bf,
    float* __restrict__ a_s, float* __restrict__ a_v) {
  int lane = threadIdx.x & 63;
  int n = blockIdx.x * 4 + (threadIdx.x >> 6);
  float acc = 0, a0 = 0, a1 = 0, a2 = 0;
  int beg = __builtin_amdgcn_readfirstlane(offsets[n]);
  int end = __builtin_amdgcn_readfirstlane(offsets[n + 1]);
  if (beg < end) {
    const float* rp0 = rec8 + (size_t)beg * 8;
    float4 rA = *(const float4*)rp0;
    float2 rB = *(const float2*)(rp0 + 4);
    int i1 = beg + (beg + 1 < end ? 1 : 0);
    const float* rp1 = rec8 + (size_t)i1 * 8;
    float4 nA = *(const float4*)rp1;
    float2 nB = *(const float2*)(rp1 + 4);
    uint2 t2 = *(const uint2*)(T0 + __float_as_int(rB.y) + (lane << 1));
    ushort16 su = s_bf[((size_t)__float_as_int(rA.x) << 6) + lane];
#pragma unroll 2
    for (int idx = beg; idx < end; ++idx) {
      uint2 pt2 = *(const uint2*)(T0 + __float_as_int(nB.y) + (lane << 1));
      ushort16 psu = s_bf[((size_t)__float_as_int(nA.x) << 6) + lane];
      int i2 = (idx + 2 < end) ? idx + 2 : end - 1;
      const float* rp2 = rec8 + (size_t)i2 * 8;
      float4 fA = *(const float4*)rp2;
      float2 fB = *(const float2*)(rp2 + 4);
      float frac = rB.x;
      float w0 = fmaf(frac, bflo(t2.x), bfhi(t2.x));
      float w1 = fmaf(frac, bflo(t2.y), bfhi(t2.y));
      float sv = __uint_as_float((uint32)su << 16);
      acc += w0 * sv;
      float t = w1 * sv;
      a0 += t * rA.y; a1 += t * rA.z; a2 += t * rA.w;
      rA = nA; rB = nB; nA = fA; nB = fB; t2 = pt2; su = psu;
    }
  }
  a_s[n * 64 + lane] = acc * INV_NORM;
  *(float4*)(a_v + ((size_t)n << 8) + (lane << 2)) =
      make_float4(a0 * INV_NORM, a1 * INV_NORM, a2 * INV_NORM, 0.f);
}

// ---------------- layer aggregation (bf16 gathers; a_v [n][128][4]) ----------------
__global__ __launch_bounds__(256, 6) void k_agg_layer(
    const float* __restrict__ cnoise, const float* __restrict__ nsw,
    const int* __restrict__ offsets, const float* __restrict__ rec8,
    const uint32* __restrict__ TS, const uint32* __restrict__ TU,
    const ushort16* __restrict__ sh_bf, const uint32* __restrict__ vh_bf,
    float* __restrict__ a_s, float* __restrict__ a_v) {
  int lane = threadIdx.x & 63;
  int n = blockIdx.x * 4 + (threadIdx.x >> 6);
  int vc = lane & 31;
  bool low = lane < 32;
  float cn = cnoise[0];
  float scale_s = 1.f + cn * nsw[lane];
  float scale_v = 1.f + cn * nsw[64 + vc];

  float ms = 0;
  float av0 = 0, av1 = 0, av2 = 0;
  float ms2 = 0;
  float b0 = 0, b1 = 0, b2 = 0;
  int beg = __builtin_amdgcn_readfirstlane(offsets[n]);
  int end = __builtin_amdgcn_readfirstlane(offsets[n + 1]);
  if (beg < end) {
    const float* rp0 = rec8 + (size_t)beg * 8;
    float4 rA = *(const float4*)rp0;
    float2 rB = *(const float2*)(rp0 + 4);
    int i1 = beg + (beg + 1 < end ? 1 : 0);
    const float* rp1 = rec8 + (size_t)i1 * 8;
    float4 nA = *(const float4*)rp1;
    float2 nB = *(const float2*)(rp1 + 4);
    int src0 = __float_as_int(rA.x);
    int qo0 = __float_as_int(rB.y);
    uint2 tS = *(const uint2*)(TS + qo0 + (lane << 1));
    uint2 tU = *(const uint2*)(TU + qo0 + (lane << 1));
    ushort16 su = sh_bf[((size_t)src0 << 6) + lane];
    uint2 vv = *(const uint2*)(vh_bf + ((size_t)src0 << 6) + (vc << 1));
#pragma unroll 2
    for (int idx = beg; idx < end; ++idx) {
      int nsrc = __float_as_int(nA.x);
      int nqo = __float_as_int(nB.y);
      uint2 ptS = *(const uint2*)(TS + nqo + (lane << 1));
      uint2 ptU = *(const uint2*)(TU + nqo + (lane << 1));
      ushort16 psu = sh_bf[((size_t)nsrc << 6) + lane];
      uint2 pvv = *(const uint2*)(vh_bf + ((size_t)nsrc << 6) + (vc << 1));
      int i2 = (idx + 2 < end) ? idx + 2 : end - 1;
      const float* rp2 = rec8 + (size_t)i2 * 8;
      float4 fA = *(const float4*)rp2;
      float2 fB = *(const float2*)(rp2 + 4);
      float frac = rB.x;
      float y0 = rA.y, y1 = rA.z, y2 = rA.w;
      float wS  = fmaf(frac, bflo(tS.x), bfhi(tS.x));
      float wSV = fmaf(frac, bflo(tS.y), bfhi(tS.y));
      float wA  = fmaf(frac, bflo(tU.x), bfhi(tU.x));
      float wB  = fmaf(frac, bflo(tU.y), bfhi(tU.y));
      float ss = __uint_as_float((uint32)su << 16);
      float v0 = bfhi(vv.x), v1 = bflo(vv.x), v2 = bfhi(vv.y);
      ms += wS * ss;
      float t = wSV * ss;
      av0 += t * y0; av1 += t * y1; av2 += t * y2;
      float vdot = v0 * y0 + v1 * y1 + v2 * y2;
      ms2 += wA * vdot;  // garbage on high lanes, never written
      float cx = v1 * y2 - v2 * y1;
      float cy = v2 * y0 - v0 * y2;
      float cz = v0 * y1 - v1 * y0;
      float m0 = low ? v0 : cx;
      float m1 = low ? v1 : cy;
      float m2 = low ? v2 : cz;
      float wM = low ? wB : wA;
      b0 += wM * m0; b1 += wM * m1; b2 += wM * m2;
      rA = nA; rB = nB; nA = fA; nB = fB;
      tS = ptS; tU = ptU; su = psu; vv = pvv;
    }
  }
  float fs = scale_s * INV_NORM;
  float fv = scale_v * INV_NORM;
  a_s[n * 96 + lane] = ms * fs;
  float* avn = a_v + ((size_t)n << 9);
  *(float4*)(avn + (lane << 2)) = make_float4(av0 * fs, av1 * fs, av2 * fs, 0.f);
  if (low) {
    a_s[n * 96 + 64 + vc] = ms2 * fv;
    *(float4*)(avn + ((64 + vc) << 2)) = make_float4(b0 * fv, b1 * fv, b2 * fv, 0.f);
  } else {
    *(float4*)(avn + ((96 + vc) << 2)) = make_float4(b0 * fv, b1 * fv, b2 * fv, 0.f);
  }
}

// ---------------- init projections: LDS-staged matvecs (+ bf16 mirrors) ----------------
__global__ __launch_bounds__(256, 4) void k_init_s(
    const float* __restrict__ a_s, const float* __restrict__ s_feat,
    const float* __restrict__ Ws0, const float* __restrict__ Wself0,
    float* __restrict__ sh, ushort16* __restrict__ sh_bf) {
  __shared__ float W1[64 * 64];
  __shared__ float W2[64 * 64];
  __shared__ float La[8 * 64];
  __shared__ float Lf[8 * 64];
  int tid = threadIdx.x;
  for (int i = tid; i < 1024; i += 256) {
    ((float4*)W1)[i] = ((const float4*)Ws0)[i];
    ((float4*)W2)[i] = ((const float4*)Wself0)[i];
  }
  int base = blockIdx.x * 8;
  for (int i = tid; i < 512; i += 256) {
    La[i] = a_s[(size_t)base * 64 + i];
    Lf[i] = s_feat[(size_t)base * 64 + i];
  }
  __syncthreads();
  int d = tid & 63, g = tid >> 6;
  int n0 = base + g * 2;
  const float* A0 = La + g * 128;
  const float* A1 = A0 + 64;
  const float* F0 = Lf + g * 128;
  const float* F1 = F0 + 64;
  float a0 = 0, a1 = 0;
#pragma unroll 8
  for (int c = 0; c < 64; ++c) {
    float w1 = W1[c * 64 + d], w2 = W2[c * 64 + d];
    a0 += A0[c] * w1 + F0[c] * w2;
    a1 += A1[c] * w1 + F1[c] * w2;
  }
  sh[(size_t)n0 * 64 + d] = a0;
  sh[(size_t)(n0 + 1) * 64 + d] = a1;
  sh_bf[(size_t)n0 * 64 + d] = f2bf(a0);
  sh_bf[(size_t)(n0 + 1) * 64 + d] = f2bf(a1);
}

__global__ __launch_bounds__(256, 4) void k_init_v(
    const float* __restrict__ a_v, const float* __restrict__ Wv0,
    float* __restrict__ vh, uint32* __restrict__ vh_bf) {
  __shared__ float W[64 * 32];  // 8KB
  int tid = threadIdx.x;
  for (int i = tid; i < 512; i += 256) ((float4*)W)[i] = ((const float4*)Wv0)[i];
  __syncthreads();
  int d = tid & 31, g = tid >> 5;
  int n = blockIdx.x * 8 + g;
  const float4* av = (const float4*)(a_v + ((size_t)n << 8));
  float x = 0, y = 0, z = 0;
#pragma unroll 4
  for (int c = 0; c < 64; ++c) {
    float4 a = av[c];
    float w = W[c * 32 + d];
    x += a.x * w; y += a.y * w; z += a.z * w;
  }
  *(float4*)(vh + ((size_t)n << 7) + (d << 2)) = make_float4(x, y, z, 0.f);
  *(uint2*)(vh_bf + ((size_t)n << 6) + (d << 1)) = make_uint2(packbf(x, y), packbf(z, 0.f));
}

// ---------------- mix/self/skip: LDS-staged matvecs (+ bf16 mirrors) ----------------
__global__ __launch_bounds__(256, 4) void k_mix_s(
    const float* __restrict__ a_s, const float* __restrict__ sh_in,
    const float* __restrict__ Wmix_s, const float* __restrict__ Wself_s,
    const float* __restrict__ nsw, const float* __restrict__ skw,
    const float* __restrict__ skb, const float* __restrict__ cnoise,
    float* __restrict__ sh_out, ushort16* __restrict__ sh_bf_out) {
  __shared__ float Wm[96 * 64];   // 24KB
  __shared__ float Wsf[64 * 64];  // 16KB (scale folded in)
  __shared__ float La[8 * 96];    // 3KB
  int tid = threadIdx.x;
  float cn = cnoise[0];
  for (int i = tid; i < 96 * 16; i += 256) ((float4*)Wm)[i] = ((const float4*)Wmix_s)[i];
  for (int i = tid; i < 64 * 16; i += 256) {
    float4 wv = ((const float4*)Wself_s)[i];
    int c = i >> 4;
    float sc = 1.f + cn * nsw[c];
    wv.x *= sc; wv.y *= sc; wv.z *= sc; wv.w *= sc;
    ((float4*)Wsf)[i] = wv;
  }
  int base = blockIdx.x * 8;
  for (int i = tid; i < 8 * 96; i += 256) La[i] = a_s[(size_t)base * 96 + i];
  __syncthreads();
  int d = tid & 63, g = tid >> 6;
  int n0 = base + g * 2;
  const float* A0 = La + (g * 2) * 96;
  const float* A1 = A0 + 96;
  const float* s0p = sh_in + (size_t)n0 * 64;
  const float* s1p = s0p + 64;
  float acc0 = 0, acc1 = 0;
#pragma unroll 8
  for (int c = 0; c < 96; ++c) {
    float w = Wm[c * 64 + d];
    acc0 += A0[c] * w;
    acc1 += A1[c] * w;
  }
#pragma unroll 8
  for (int c = 0; c < 64; ++c) {
    float w = Wsf[c * 64 + d];
    acc0 += s0p[c] * w;
    acc1 += s1p[c] * w;
  }
  float g1 = sigmoidf_(skb[d] + cn * skw[d]);
  float g2 = sigmoidf_(skb[64 + d] + cn * skw[64 + d]);
  float o0 = g1 * s0p[d] + g2 * acc0;
  float o1 = g1 * s1p[d] + g2 * acc1;
  sh_out[(size_t)n0 * 64 + d] = o0;
  sh_out[(size_t)(n0 + 1) * 64 + d] = o1;
  sh_bf_out[(size_t)n0 * 64 + d] = f2bf(o0);
  sh_bf_out[(size_t)(n0 + 1) * 64 + d] = f2bf(o1);
}

__global__ __launch_bounds__(256, 4) void k_mix_v(
    const float* __restrict__ a_v, const float* __restrict__ vh_in,
    const float* __restrict__ Wmix_v, const float* __restrict__ Wself_v,
    const float* __restrict__ nsw, const float* __restrict__ skw,
    const float* __restrict__ skb, const float* __restrict__ cnoise,
    float* __restrict__ vh_out, uint32* __restrict__ vh_bf_out) {
  __shared__ float Wm[128 * 32];   // 16KB
  __shared__ float Wsf[32 * 32];   // 4KB (scale folded in)
  int tid = threadIdx.x;
  float cn = cnoise[0];
  for (int i = tid; i < 128 * 8; i += 256) ((float4*)Wm)[i] = ((const float4*)Wmix_v)[i];
  for (int i = tid; i < 32 * 8; i += 256) {
    float4 wv = ((const float4*)Wself_v)[i];
    int c = i >> 3;
    float sc = 1.f + cn * nsw[64 + c];
    wv.x *= sc; wv.y *= sc; wv.z *= sc; wv.w *= sc;
    ((float4*)Wsf)[i] = wv;
  }
  __syncthreads();
  int d = tid & 31, g = tid >> 5;
  int n = blockIdx.x * 8 + g;
  const float4* av = (const float4*)(a_v + ((size_t)n << 9));
  const float4* vr = (const float4*)(vh_in + ((size_t)n << 7));
  float x = 0, y = 0, z = 0;
#pragma unroll 4
  for (int c = 0; c < 128; ++c) {
    float4 a = av[c];
    float w = Wm[c * 32 + d];
    x += a.x * w; y += a.y * w; z += a.z * w;
  }
#pragma unroll 4
  for (int c = 0; c < 32; ++c) {
    float4 vv = vr[c];
    float w = Wsf[c * 32 + d];
    x += vv.x * w; y += vv.y * w; z += vv.z * w;
  }
  float g3 = sigmoidf_(skb[128 + d] + cn * skw[128 + d]);
  float g4 = sigmoidf_(skb[160 + d] + cn * skw[160 + d]);
  float4 vi = vr[d];
  float ox = g3 * vi.x + g4 * x;
  float oy = g3 * vi.y + g4 * y;
  float oz = g3 * vi.z + g4 * z;
  *(float4*)(vh_out + ((size_t)n << 7) + (d << 2)) = make_float4(ox, oy, oz, 0.f);
  *(uint2*)(vh_bf_out + ((size_t)n << 6) + (d << 1)) = make_uint2(packbf(ox, oy), packbf(oz, 0.f));
}

// ---------------- output ----------------
__global__ void k_out(const float* __restrict__ vh, const float* __restrict__ w_out,
                      const float* __restrict__ gain, float* __restrict__ out) {
  int tid = blockIdx.x * 256 + threadIdx.x;  // < NA*3
  int n = tid / 3, i = tid - n * 3;
  float acc = 0;
  for (int c = 0; c < 32; ++c) acc += vh[((size_t)n << 7) + c * 4 + i] * w_out[c];
  out[tid] = acc * gain[0];
}

extern "C" void kernel_launch(void* const* d_in, const int* in_sizes, int n_in,
                              void* d_out, int out_size, void* d_ws, size_t ws_size,
                              hipStream_t stream) {
  (void)in_sizes; (void)n_in; (void)out_size; (void)ws_size;
  const float* pos     = (const float*)d_in[0];
  const float* cn      = (const float*)d_in[1];
  const int*   types   = (const int*)d_in[2];
  const int*   rad     = (const int*)d_in[3];
  const int*   bon     = (const int*)d_in[4];
  const float* atom_tab= (const float*)d_in[5];
  const float* bond_tab= (const float*)d_in[6];
  const float* ns0_w   = (const float*)d_in[7];
  const float* We0     = (const float*)d_in[8];
  const float* We1     = (const float*)d_in[9];
  const float* Wself0  = (const float*)d_in[10];
  const float* Ws0     = (const float*)d_in[11];
  const float* Wv0     = (const float*)d_in[12];
  const float* ns_w    = (const float*)d_in[13];
  const float* We_ss   = (const float*)d_in[14];
  const float* We_vs   = (const float*)d_in[15];
  const float* We_sv   = (const float*)d_in[16];
  const float* We_vv   = (const float*)d_in[17];
  const float* We_vx   = (const float*)d_in[18];
  const float* Wmix_s  = (const float*)d_in[19];
  const float* Wmix_v  = (const float*)d_in[20];
  const float* Wself_s = (const float*)d_in[21];
  const float* Wself_v = (const float*)d_in[22];
  const float* skip_w  = (const float*)d_in[23];
  const float* skip_b  = (const float*)d_in[24];
  const float* w_out   = (const float*)d_in[25];
  const float* gain    = (const float*)d_in[26];

  char* ws = (char*)d_ws;
  size_t o = 0;
  auto alloc = [&](size_t bytes) -> void* {
    void* p = ws + o;
    o += (bytes + 255) & ~(size_t)255;
    return p;
  };
  float* s_feat  = (float*)alloc((size_t)NA * 64 * 4);
  ushort16* s_bf = (ushort16*)alloc((size_t)NA * 64 * 2);
  float* a_s     = (float*)alloc((size_t)NA * 96 * 4);
  float* a_v     = (float*)alloc((size_t)NA * 512 * 4);  // [n][128][4]; agg0 uses [n][64][4]
  float* sh0     = (float*)alloc((size_t)NA * 64 * 4);
  float* sh1     = (float*)alloc((size_t)NA * 64 * 4);
  ushort16* shbf0= (ushort16*)alloc((size_t)NA * 64 * 2);
  ushort16* shbf1= (ushort16*)alloc((size_t)NA * 64 * 2);
  float* vh0     = (float*)alloc((size_t)NA * 128 * 4);  // [n][32][4]
  float* vh1     = (float*)alloc((size_t)NA * 128 * 4);
  uint32* vhbf0  = (uint32*)alloc((size_t)NA * 64 * 4);  // [n][32][2] uints
  uint32* vhbf1  = (uint32*)alloc((size_t)NA * 64 * 4);
  int* count     = (int*)alloc((size_t)NA * 4);
  int* partial   = (int*)alloc((size_t)64 * 4);
  int* offsets   = (int*)alloc((size_t)(NA + 1) * 4);
  int* cursor    = (int*)alloc((size_t)NA * 4);
  int* sorted    = (int*)alloc((size_t)ET * 4);
  float* rec8    = (float*)alloc((size_t)ET * 32);
  uint32* tabs   = (uint32*)alloc((size_t)5 * TBLU * 4);
  float* shb[2]  = {sh0, sh1};
  ushort16* shbf[2] = {shbf0, shbf1};
  float* vhb[2]  = {vh0, vh1};
  uint32* vhbf[2]= {vhbf0, vhbf1};

  // CSR build + tables
  k_zero<<<NA / 256, 256, 0, stream>>>(count);
  k_hist<<<ET / 256, 256, 0, stream>>>(rad, bon, count);
  k_scan1<<<64, 256, 0, stream>>>(count, partial);
  k_scan2<<<1, 1, 0, stream>>>(partial);
  k_scan3<<<64, 256, 0, stream>>>(count, partial, offsets, cursor);
  k_fill<<<ET / 256, 256, 0, stream>>>(rad, bon, cursor, sorted);
  k_edge_pre<<<ET / 256, 256, 0, stream>>>(pos, rad, bon, sorted, rec8);
  k_build<<<dim3(BINS, 5, 2), 64, 0, stream>>>(We0, We1, We_ss, We_vs, We_sv, We_vv, We_vx,
                                               bond_tab, tabs);

  k_embed<<<NA * 64 / 256, 256, 0, stream>>>(atom_tab, types, ns0_w, cn, s_feat, s_bf);
  k_agg0<<<NA / 4, 256, 0, stream>>>(offsets, rec8, tabs, s_bf, a_s, a_v);
  k_init_s<<<NA / 8, 256, 0, stream>>>(a_s, s_feat, Ws0, Wself0, shb[0], shbf[0]);
  k_init_v<<<NA / 8, 256, 0, stream>>>(a_v, Wv0, vhb[0], vhbf[0]);

  for (int l = 0; l < 2; ++l) {
    int bin = l & 1, bout = 1 - bin;
    const uint32* TS = tabs + (size_t)(1 + 2 * l) * TBLU;
    const uint32* TU = tabs + (size_t)(2 + 2 * l) * TBLU;
    k_agg_layer<<<NA / 4, 256, 0, stream>>>(
        cn, ns_w + l * 96, offsets, rec8, TS, TU, shbf[bin], vhbf[bin], a_s, a_v);
    k_mix_s<<<NA / 8, 256, 0, stream>>>(
        a_s, shb[bin], Wmix_s + l * 96 * 64, Wself_s + l * 64 * 64,
        ns_w + l * 96, skip_w + l * 192, skip_b + l * 192, cn, shb[bout], shbf[bout]);
    k_mix_v<<<NA / 8, 256, 0, stream>>>(
        a_v, vhb[bin], Wmix_v + l * 128 * 32, Wself_v + l * 32 * 32,
        ns_w + l * 96, skip_w + l * 192, skip_b + l * 192, cn, vhb[bout], vhbf[bout]);
  }
  k_out<<<NA * 3 / 256, 256, 0, stream>>>(vhb[0], w_out, gain, (float*)d_out);
}

// Round 13
// 470.664 us; speedup vs baseline: 2.2236x; 1.1193x over previous
//
#include <hip/hip_runtime.h>
#include <math.h>

#define NA 16384
#define ER 524288
#define EB 32768
#define ET 557056
#define INV_NORM 0.17149858514250882f   // 1/sqrt((ER+EB)/NA) = 1/sqrt(34)
#define SQRT3 1.7320508075688772f
#define RB_STEP (1.5f/9.0f)
#define BINS 512
#define DMAX 2.5f
#define INV_H ((float)BINS / DMAX)
#define T0U (2 * BINS * 128)    // agg0 table: [2][BINS][64][2] uints
#define TLU (2 * BINS * 256)    // layer table: [2][BINS][64][4] uints

typedef unsigned int uint32;
typedef unsigned short ushort16;

__device__ __forceinline__ float sigmoidf_(float x) { return 1.f / (1.f + __expf(-x)); }

__device__ __forceinline__ ushort16 f2bf(float x) {
  uint32 u = __float_as_uint(x);
  u = u + 0x7FFFu + ((u >> 16) & 1u);
  return (ushort16)(u >> 16);
}
__device__ __forceinline__ uint32 packbf(float hi, float lo) {
  return ((uint32)f2bf(hi) << 16) | (uint32)f2bf(lo);
}
__device__ __forceinline__ float bfhi(uint32 u) { return __uint_as_float(u & 0xFFFF0000u); }
__device__ __forceinline__ float bflo(uint32 u) { return __uint_as_float(u << 16); }

// ---------------- CSR build ----------------
__global__ void k_zero(int* __restrict__ count) {
  count[blockIdx.x * 256 + threadIdx.x] = 0;
}

__global__ void k_hist(const int* __restrict__ rad, const int* __restrict__ bon, int* __restrict__ count) {
  int e = blockIdx.x * 256 + threadIdx.x;
  int d = (e < ER) ? rad[ER + e] : bon[EB + (e - ER)];
  atomicAdd(&count[d], 1);
}

__global__ void k_scan1(const int* __restrict__ count, int* __restrict__ partial) {
  __shared__ int red[256];
  int b = blockIdx.x, t = threadIdx.x;
  red[t] = count[b * 256 + t];
  __syncthreads();
  for (int s = 128; s > 0; s >>= 1) {
    if (t < s) red[t] += red[t + s];
    __syncthreads();
  }
  if (t == 0) partial[b] = red[0];
}

__global__ void k_scan2(int* __restrict__ partial) {
  int run = 0;
  for (int i = 0; i < 64; ++i) { int c = partial[i]; partial[i] = run; run += c; }
}

__global__ void k_scan3(const int* __restrict__ count, const int* __restrict__ partial,
                        int* __restrict__ offsets, int* __restrict__ cursor) {
  __shared__ int sc[256];
  int b = blockIdx.x, t = threadIdx.x;
  int v = count[b * 256 + t];
  sc[t] = v;
  __syncthreads();
  for (int off = 1; off < 256; off <<= 1) {
    int x = (t >= off) ? sc[t - off] : 0;
    __syncthreads();
    sc[t] += x;
    __syncthreads();
  }
  int excl = sc[t] - v + partial[b];
  offsets[b * 256 + t] = excl;
  cursor[b * 256 + t] = excl;
  if (b == 63 && t == 255) offsets[NA] = excl + v;
}

// ---------------- fused fill + per-edge record precompute ----------------
// record[slot] (32B): {src, Y0, Y1, Y2, frac, qoffL(uint elems, layer scale), pad, pad}
// agg0 table offset = qoffL >> 1
__global__ void k_fill_pre(const int* __restrict__ rad, const int* __restrict__ bon,
                           int* __restrict__ cursor, const float* __restrict__ pos,
                           float* __restrict__ rec8) {
  int e = blockIdx.x * 256 + threadIdx.x;
  int src, dst, v;
  if (e < ER) { src = rad[e]; dst = rad[ER + e]; v = 0; }
  else        { src = bon[e - ER]; dst = bon[EB + e - ER]; v = 1; }
  float dx = pos[src * 3] - pos[dst * 3];
  float dy = pos[src * 3 + 1] - pos[dst * 3 + 1];
  float dz = pos[src * 3 + 2] - pos[dst * 3 + 2];
  float dist = sqrtf(dx * dx + dy * dy + dz * dz + 1e-12f);
  float inv = 1.f / dist;
  float fq = fminf(dist * INV_H, BINS - 1.001f);
  int q = (int)fq;
  float frac = fq - (float)q;
  int qoffL = (v * BINS + q) << 8;   // 256 uints per layer row
  int slot = atomicAdd(&cursor[dst], 1);
  float* rp = rec8 + (size_t)slot * 8;
  *(float4*)rp = make_float4(__int_as_float(src), SQRT3 * dx * inv, SQRT3 * dy * inv, SQRT3 * dz * inv);
  rp[4] = frac;
  rp[5] = __int_as_float(qoffL);
}

// ---------------- bf16 tables, bond base folded ----------------
// t=0: T0 [2][BINS][64][2]: {pair(w0), pair(w1)}
// t=1,2: TL[l] [2][BINS][64][4]: {pair(w_ss), pair(w_sv), pair(uA), pair(uB)}
//        lane<32: uA=w_vs uB=w_vv ; lane>=32: uA=w_vx uB=0
__global__ void k_build(const float* __restrict__ We0, const float* __restrict__ We1,
                        const float* __restrict__ We_ss, const float* __restrict__ We_vs,
                        const float* __restrict__ We_sv, const float* __restrict__ We_vv,
                        const float* __restrict__ We_vx, const float* __restrict__ bond_tab,
                        uint32* __restrict__ T0, uint32* __restrict__ TL) {
  int q = blockIdx.x, t = blockIdx.y, v = blockIdx.z, c = threadIdx.x;
  float d0 = q * (DMAX / BINS), d1 = (q + 1) * (DMAX / BINS);
  float rb0[8], rb1[8];
#pragma unroll
  for (int k = 0; k < 8; ++k) {
    float f0 = (d0 - (k + 1) * RB_STEP) * (1.f / RB_STEP);
    float f1 = (d1 - (k + 1) * RB_STEP) * (1.f / RB_STEP);
    rb0[k] = 1.12f * __expf(-f0 * f0);
    rb1[k] = 1.12f * __expf(-f1 * f1);
  }
  if (t == 0) {
    float ba = 0, bb = 0, a0 = 0, a1 = 0, b0 = 0, b1 = 0;
#pragma unroll
    for (int k = 0; k < 8; ++k) {
      float bt = bond_tab[v * 8 + k];
      float av_lo = We0[k * 64 + c], av_hi = We0[(8 + k) * 64 + c];
      float bv_lo = We1[k * 64 + c], bv_hi = We1[(8 + k) * 64 + c];
      ba += bt * av_lo; bb += bt * bv_lo;
      a0 += rb0[k] * av_hi; a1 += rb1[k] * av_hi;
      b0 += rb0[k] * bv_hi; b1 += rb1[k] * bv_hi;
    }
    uint32* o = T0 + (((size_t)v * BINS + q) << 7) + c * 2;
    o[0] = packbf(ba + a0, a1 - a0);
    o[1] = packbf(bb + b0, b1 - b0);
  } else {
    int l = t - 1;
    const float* Wss = We_ss + l * 1024;
    const float* Wsv = We_sv + l * 1024;
    const float* WA = (c < 32) ? (We_vs + l * 512) : (We_vx + l * 512);
    const float* WB = (c < 32) ? (We_vv + l * 512) : nullptr;
    int cu = c & 31;
    float sa = 0, sb = 0, s0 = 0, s1 = 0, t0 = 0, t1 = 0;
    float ua = 0, ub = 0, u0 = 0, u1 = 0, w0 = 0, w1 = 0;
#pragma unroll
    for (int k = 0; k < 8; ++k) {
      float bt = bond_tab[v * 8 + k];
      float ss_lo = Wss[k * 64 + c], ss_hi = Wss[(8 + k) * 64 + c];
      float sv_lo = Wsv[k * 64 + c], sv_hi = Wsv[(8 + k) * 64 + c];
      sa += bt * ss_lo; sb += bt * sv_lo;
      s0 += rb0[k] * ss_hi; s1 += rb1[k] * ss_hi;
      t0 += rb0[k] * sv_hi; t1 += rb1[k] * sv_hi;
      float a_lo = WA[k * 32 + cu], a_hi = WA[(8 + k) * 32 + cu];
      ua += bt * a_lo;
      u0 += rb0[k] * a_hi; u1 += rb1[k] * a_hi;
      if (WB) {
        float b_lo = WB[k * 32 + cu], b_hi = WB[(8 + k) * 32 + cu];
        ub += bt * b_lo;
        w0 += rb0[k] * b_hi; w1 += rb1[k] * b_hi;
      }
    }
    uint32* o = TL + (size_t)l * TLU + (((size_t)v * BINS + q) << 8) + c * 4;
    o[0] = packbf(sa + s0, s1 - s0);
    o[1] = packbf(sb + t0, t1 - t0);
    o[2] = packbf(ua + u0, u1 - u0);
    o[3] = WB ? packbf(ub + w0, w1 - w0) : 0u;
  }
}

// ---------------- embedding (f32 + bf16 mirror) ----------------
__global__ void k_embed(const float* __restrict__ atom_tab, const int* __restrict__ types,
                        const float* __restrict__ ns0_w, const float* __restrict__ cnoise,
                        float* __restrict__ s_feat, ushort16* __restrict__ s_bf) {
  int tid = blockIdx.x * 256 + threadIdx.x;
  int n = tid >> 6, c = tid & 63;
  float cn = cnoise[0];
  float v = atom_tab[types[n] * 64 + c] * (1.f + cn * ns0_w[c]);
  s_feat[tid] = v;
  s_bf[tid] = f2bf(v);
}

// ---------------- initial aggregation (3-stage pipeline) ----------------
__global__ __launch_bounds__(256, 8) void k_agg0(
    const int* __restrict__ offsets, const float* __restrict__ rec8,
    const uint32* __restrict__ T0, const ushort16* __restrict__ s_bf,
    float* __restrict__ a_s, float* __restrict__ a_v) {
  int lane = threadIdx.x & 63;
  int n = blockIdx.x * 4 + (threadIdx.x >> 6);
  float acc = 0, a0 = 0, a1 = 0, a2 = 0;
  int beg = __builtin_amdgcn_readfirstlane(offsets[n]);
  int end = __builtin_amdgcn_readfirstlane(offsets[n + 1]);
  if (beg < end) {
    int last = end - 1;
    int e1 = (beg + 1 < end) ? beg + 1 : last;
    int e2 = (beg + 2 < end) ? beg + 2 : last;
    const float* p0 = rec8 + (size_t)beg * 8;
    const float* p1 = rec8 + (size_t)e1 * 8;
    const float* p2 = rec8 + (size_t)e2 * 8;
    float4 rA0 = *(const float4*)p0; float2 rB0 = *(const float2*)(p0 + 4);
    float4 rA1 = *(const float4*)p1; float2 rB1 = *(const float2*)(p1 + 4);
    float4 rA2 = *(const float4*)p2; float2 rB2 = *(const float2*)(p2 + 4);
    uint2 t0 = *(const uint2*)(T0 + (__float_as_int(rB0.y) >> 1) + (lane << 1));
    ushort16 s0 = s_bf[((size_t)__float_as_int(rA0.x) << 6) + lane];
    uint2 t1 = *(const uint2*)(T0 + (__float_as_int(rB1.y) >> 1) + (lane << 1));
    ushort16 s1 = s_bf[((size_t)__float_as_int(rA1.x) << 6) + lane];
#pragma unroll 3
    for (int idx = beg; idx < end; ++idx) {
      // issue stage-2 gathers, prefetch rec idx+3
      uint2 t2 = *(const uint2*)(T0 + (__float_as_int(rB2.y) >> 1) + (lane << 1));
      ushort16 s2 = s_bf[((size_t)__float_as_int(rA2.x) << 6) + lane];
      int e3 = (idx + 3 < end) ? idx + 3 : last;
      const float* p3 = rec8 + (size_t)e3 * 8;
      float4 rA3 = *(const float4*)p3; float2 rB3 = *(const float2*)(p3 + 4);
      // compute current
      float frac = rB0.x;
      float w0 = fmaf(frac, bflo(t0.x), bfhi(t0.x));
      float w1 = fmaf(frac, bflo(t0.y), bfhi(t0.y));
      float sv = __uint_as_float((uint32)s0 << 16);
      acc += w0 * sv;
      float t = w1 * sv;
      a0 += t * rA0.y; a1 += t * rA0.z; a2 += t * rA0.w;
      // rotate
      rA0 = rA1; rB0 = rB1; rA1 = rA2; rB1 = rB2; rA2 = rA3; rB2 = rB3;
      t0 = t1; s0 = s1; t1 = t2; s1 = s2;
    }
  }
  a_s[n * 64 + lane] = acc * INV_NORM;
  *(float4*)(a_v + ((size_t)n << 8) + (lane << 2)) =
      make_float4(a0 * INV_NORM, a1 * INV_NORM, a2 * INV_NORM, 0.f);
}

// ---------------- layer aggregation (3-stage pipeline, merged table) ----------------
__global__ __launch_bounds__(256, 8) void k_agg_layer(
    const float* __restrict__ cnoise, const float* __restrict__ nsw,
    const int* __restrict__ offsets, const float* __restrict__ rec8,
    const uint32* __restrict__ TL, const ushort16* __restrict__ sh_bf,
    const uint32* __restrict__ vh_bf,
    float* __restrict__ a_s, float* __restrict__ a_v) {
  int lane = threadIdx.x & 63;
  int n = blockIdx.x * 4 + (threadIdx.x >> 6);
  int vc = lane & 31;
  bool low = lane < 32;
  float cn = cnoise[0];
  float scale_s = 1.f + cn * nsw[lane];
  float scale_v = 1.f + cn * nsw[64 + vc];

  float ms = 0;
  float av0 = 0, av1 = 0, av2 = 0;
  float ms2 = 0;
  float b0 = 0, b1 = 0, b2 = 0;
  int beg = __builtin_amdgcn_readfirstlane(offsets[n]);
  int end = __builtin_amdgcn_readfirstlane(offsets[n + 1]);
  if (beg < end) {
    int last = end - 1;
    int e1 = (beg + 1 < end) ? beg + 1 : last;
    int e2 = (beg + 2 < end) ? beg + 2 : last;
    const float* p0 = rec8 + (size_t)beg * 8;
    const float* p1 = rec8 + (size_t)e1 * 8;
    const float* p2 = rec8 + (size_t)e2 * 8;
    float4 rA0 = *(const float4*)p0; float2 rB0 = *(const float2*)(p0 + 4);
    float4 rA1 = *(const float4*)p1; float2 rB1 = *(const float2*)(p1 + 4);
    float4 rA2 = *(const float4*)p2; float2 rB2 = *(const float2*)(p2 + 4);
    uint4 t0 = *(const uint4*)(TL + __float_as_int(rB0.y) + (lane << 2));
    ushort16 s0 = sh_bf[((size_t)__float_as_int(rA0.x) << 6) + lane];
    uint2 v0 = *(const uint2*)(vh_bf + ((size_t)__float_as_int(rA0.x) << 6) + (vc << 1));
    uint4 t1 = *(const uint4*)(TL + __float_as_int(rB1.y) + (lane << 2));
    ushort16 s1 = sh_bf[((size_t)__float_as_int(rA1.x) << 6) + lane];
    uint2 v1 = *(const uint2*)(vh_bf + ((size_t)__float_as_int(rA1.x) << 6) + (vc << 1));
#pragma unroll 3
    for (int idx = beg; idx < end; ++idx) {
      // issue stage-2 gathers, prefetch rec idx+3
      uint4 t2 = *(const uint4*)(TL + __float_as_int(rB2.y) + (lane << 2));
      ushort16 s2 = sh_bf[((size_t)__float_as_int(rA2.x) << 6) + lane];
      uint2 v2 = *(const uint2*)(vh_bf + ((size_t)__float_as_int(rA2.x) << 6) + (vc << 1));
      int e3 = (idx + 3 < end) ? idx + 3 : last;
      const float* p3 = rec8 + (size_t)e3 * 8;
      float4 rA3 = *(const float4*)p3; float2 rB3 = *(const float2*)(p3 + 4);
      // compute current
      float frac = rB0.x;
      float y0 = rA0.y, y1 = rA0.z, y2 = rA0.w;
      float wS  = fmaf(frac, bflo(t0.x), bfhi(t0.x));
      float wSV = fmaf(frac, bflo(t0.y), bfhi(t0.y));
      float wA  = fmaf(frac, bflo(t0.z), bfhi(t0.z));
      float wB  = fmaf(frac, bflo(t0.w), bfhi(t0.w));
      float ss = __uint_as_float((uint32)s0 << 16);
      float vx = bfhi(v0.x), vy = bflo(v0.x), vz = bfhi(v0.y);
      ms += wS * ss;
      float t = wSV * ss;
      av0 += t * y0; av1 += t * y1; av2 += t * y2;
      float vdot = vx * y0 + vy * y1 + vz * y2;
      ms2 += wA * vdot;  // garbage on high lanes, never written
      float cx = vy * y2 - vz * y1;
      float cy = vz * y0 - vx * y2;
      float cz = vx * y1 - vy * y0;
      float m0 = low ? vx : cx;
      float m1 = low ? vy : cy;
      float m2 = low ? vz : cz;
      float wM = low ? wB : wA;
      b0 += wM * m0; b1 += wM * m1; b2 += wM * m2;
      // rotate
      rA0 = rA1; rB0 = rB1; rA1 = rA2; rB1 = rB2; rA2 = rA3; rB2 = rB3;
      t0 = t1; s0 = s1; v0 = v1; t1 = t2; s1 = s2; v1 = v2;
    }
  }
  float fs = scale_s * INV_NORM;
  float fv = scale_v * INV_NORM;
  a_s[n * 96 + lane] = ms * fs;
  float* avn = a_v + ((size_t)n << 9);
  *(float4*)(avn + (lane << 2)) = make_float4(av0 * fs, av1 * fs, av2 * fs, 0.f);
  if (low) {
    a_s[n * 96 + 64 + vc] = ms2 * fv;
    *(float4*)(avn + ((64 + vc) << 2)) = make_float4(b0 * fv, b1 * fv, b2 * fv, 0.f);
  } else {
    *(float4*)(avn + ((96 + vc) << 2)) = make_float4(b0 * fv, b1 * fv, b2 * fv, 0.f);
  }
}

// ---------------- init projections: LDS-staged matvecs (+ bf16 mirrors) ----------------
__global__ __launch_bounds__(256, 4) void k_init_s(
    const float* __restrict__ a_s, const float* __restrict__ s_feat,
    const float* __restrict__ Ws0, const float* __restrict__ Wself0,
    float* __restrict__ sh, ushort16* __restrict__ sh_bf) {
  __shared__ float W1[64 * 64];
  __shared__ float W2[64 * 64];
  __shared__ float La[8 * 64];
  __shared__ float Lf[8 * 64];
  int tid = threadIdx.x;
  for (int i = tid; i < 1024; i += 256) {
    ((float4*)W1)[i] = ((const float4*)Ws0)[i];
    ((float4*)W2)[i] = ((const float4*)Wself0)[i];
  }
  int base = blockIdx.x * 8;
  for (int i = tid; i < 512; i += 256) {
    La[i] = a_s[(size_t)base * 64 + i];
    Lf[i] = s_feat[(size_t)base * 64 + i];
  }
  __syncthreads();
  int d = tid & 63, g = tid >> 6;
  int n0 = base + g * 2;
  const float* A0 = La + g * 128;
  const float* A1 = A0 + 64;
  const float* F0 = Lf + g * 128;
  const float* F1 = F0 + 64;
  float a0 = 0, a1 = 0;
#pragma unroll 8
  for (int c = 0; c < 64; ++c) {
    float w1 = W1[c * 64 + d], w2 = W2[c * 64 + d];
    a0 += A0[c] * w1 + F0[c] * w2;
    a1 += A1[c] * w1 + F1[c] * w2;
  }
  sh[(size_t)n0 * 64 + d] = a0;
  sh[(size_t)(n0 + 1) * 64 + d] = a1;
  sh_bf[(size_t)n0 * 64 + d] = f2bf(a0);
  sh_bf[(size_t)(n0 + 1) * 64 + d] = f2bf(a1);
}

__global__ __launch_bounds__(256, 4) void k_init_v(
    const float* __restrict__ a_v, const float* __restrict__ Wv0,
    float* __restrict__ vh, uint32* __restrict__ vh_bf) {
  __shared__ float W[64 * 32];  // 8KB
  int tid = threadIdx.x;
  for (int i = tid; i < 512; i += 256) ((float4*)W)[i] = ((const float4*)Wv0)[i];
  __syncthreads();
  int d = tid & 31, g = tid >> 5;
  int n = blockIdx.x * 8 + g;
  const float4* av = (const float4*)(a_v + ((size_t)n << 8));
  float x = 0, y = 0, z = 0;
#pragma unroll 4
  for (int c = 0; c < 64; ++c) {
    float4 a = av[c];
    float w = W[c * 32 + d];
    x += a.x * w; y += a.y * w; z += a.z * w;
  }
  *(float4*)(vh + ((size_t)n << 7) + (d << 2)) = make_float4(x, y, z, 0.f);
  *(uint2*)(vh_bf + ((size_t)n << 6) + (d << 1)) = make_uint2(packbf(x, y), packbf(z, 0.f));
}

// ---------------- mix/self/skip: LDS-staged matvecs (+ bf16 mirrors) ----------------
__global__ __launch_bounds__(256, 4) void k_mix_s(
    const float* __restrict__ a_s, const float* __restrict__ sh_in,
    const float* __restrict__ Wmix_s, const float* __restrict__ Wself_s,
    const float* __restrict__ nsw, const float* __restrict__ skw,
    const float* __restrict__ skb, const float* __restrict__ cnoise,
    float* __restrict__ sh_out, ushort16* __restrict__ sh_bf_out) {
  __shared__ float Wm[96 * 64];   // 24KB
  __shared__ float Wsf[64 * 64];  // 16KB (scale folded in)
  __shared__ float La[8 * 96];    // 3KB
  int tid = threadIdx.x;
  float cn = cnoise[0];
  for (int i = tid; i < 96 * 16; i += 256) ((float4*)Wm)[i] = ((const float4*)Wmix_s)[i];
  for (int i = tid; i < 64 * 16; i += 256) {
    float4 wv = ((const float4*)Wself_s)[i];
    int c = i >> 4;
    float sc = 1.f + cn * nsw[c];
    wv.x *= sc; wv.y *= sc; wv.z *= sc; wv.w *= sc;
    ((float4*)Wsf)[i] = wv;
  }
  int base = blockIdx.x * 8;
  for (int i = tid; i < 8 * 96; i += 256) La[i] = a_s[(size_t)base * 96 + i];
  __syncthreads();
  int d = tid & 63, g = tid >> 6;
  int n0 = base + g * 2;
  const float* A0 = La + (g * 2) * 96;
  const float* A1 = A0 + 96;
  const float* s0p = sh_in + (size_t)n0 * 64;
  const float* s1p = s0p + 64;
  float acc0 = 0, acc1 = 0;
#pragma unroll 8
  for (int c = 0; c < 96; ++c) {
    float w = Wm[c * 64 + d];
    acc0 += A0[c] * w;
    acc1 += A1[c] * w;
  }
#pragma unroll 8
  for (int c = 0; c < 64; ++c) {
    float w = Wsf[c * 64 + d];
    acc0 += s0p[c] * w;
    acc1 += s1p[c] * w;
  }
  float g1 = sigmoidf_(skb[d] + cn * skw[d]);
  float g2 = sigmoidf_(skb[64 + d] + cn * skw[64 + d]);
  float o0 = g1 * s0p[d] + g2 * acc0;
  float o1 = g1 * s1p[d] + g2 * acc1;
  sh_out[(size_t)n0 * 64 + d] = o0;
  sh_out[(size_t)(n0 + 1) * 64 + d] = o1;
  sh_bf_out[(size_t)n0 * 64 + d] = f2bf(o0);
  sh_bf_out[(size_t)(n0 + 1) * 64 + d] = f2bf(o1);
}

__global__ __launch_bounds__(256, 4) void k_mix_v(
    const float* __restrict__ a_v, const float* __restrict__ vh_in,
    const float* __restrict__ Wmix_v, const float* __restrict__ Wself_v,
    const float* __restrict__ nsw, const float* __restrict__ skw,
    const float* __restrict__ skb, const float* __restrict__ cnoise,
    float* __restrict__ vh_out, uint32* __restrict__ vh_bf_out) {
  __shared__ float Wm[128 * 32];   // 16KB
  __shared__ float Wsf[32 * 32];   // 4KB (scale folded in)
  int tid = threadIdx.x;
  float cn = cnoise[0];
  for (int i = tid; i < 128 * 8; i += 256) ((float4*)Wm)[i] = ((const float4*)Wmix_v)[i];
  for (int i = tid; i < 32 * 8; i += 256) {
    float4 wv = ((const float4*)Wself_v)[i];
    int c = i >> 3;
    float sc = 1.f + cn * nsw[64 + c];
    wv.x *= sc; wv.y *= sc; wv.z *= sc; wv.w *= sc;
    ((float4*)Wsf)[i] = wv;
  }
  __syncthreads();
  int d = tid & 31, g = tid >> 5;
  int n = blockIdx.x * 8 + g;
  const float4* av = (const float4*)(a_v + ((size_t)n << 9));
  const float4* vr = (const float4*)(vh_in + ((size_t)n << 7));
  float x = 0, y = 0, z = 0;
#pragma unroll 4
  for (int c = 0; c < 128; ++c) {
    float4 a = av[c];
    float w = Wm[c * 32 + d];
    x += a.x * w; y += a.y * w; z += a.z * w;
  }
#pragma unroll 4
  for (int c = 0; c < 32; ++c) {
    float4 vv = vr[c];
    float w = Wsf[c * 32 + d];
    x += vv.x * w; y += vv.y * w; z += vv.z * w;
  }
  float g3 = sigmoidf_(skb[128 + d] + cn * skw[128 + d]);
  float g4 = sigmoidf_(skb[160 + d] + cn * skw[160 + d]);
  float4 vi = vr[d];
  float ox = g3 * vi.x + g4 * x;
  float oy = g3 * vi.y + g4 * y;
  float oz = g3 * vi.z + g4 * z;
  *(float4*)(vh_out + ((size_t)n << 7) + (d << 2)) = make_float4(ox, oy, oz, 0.f);
  *(uint2*)(vh_bf_out + ((size_t)n << 6) + (d << 1)) = make_uint2(packbf(ox, oy), packbf(oz, 0.f));
}

// ---------------- output ----------------
__global__ void k_out(const float* __restrict__ vh, const float* __restrict__ w_out,
                      const float* __restrict__ gain, float* __restrict__ out) {
  int tid = blockIdx.x * 256 + threadIdx.x;  // < NA*3
  int n = tid / 3, i = tid - n * 3;
  float acc = 0;
  for (int c = 0; c < 32; ++c) acc += vh[((size_t)n << 7) + c * 4 + i] * w_out[c];
  out[tid] = acc * gain[0];
}

extern "C" void kernel_launch(void* const* d_in, const int* in_sizes, int n_in,
                              void* d_out, int out_size, void* d_ws, size_t ws_size,
                              hipStream_t stream) {
  (void)in_sizes; (void)n_in; (void)out_size; (void)ws_size;
  const float* pos     = (const float*)d_in[0];
  const float* cn      = (const float*)d_in[1];
  const int*   types   = (const int*)d_in[2];
  const int*   rad     = (const int*)d_in[3];
  const int*   bon     = (const int*)d_in[4];
  const float* atom_tab= (const float*)d_in[5];
  const float* bond_tab= (const float*)d_in[6];
  const float* ns0_w   = (const float*)d_in[7];
  const float* We0     = (const float*)d_in[8];
  const float* We1     = (const float*)d_in[9];
  const float* Wself0  = (const float*)d_in[10];
  const float* Ws0     = (const float*)d_in[11];
  const float* Wv0     = (const float*)d_in[12];
  const float* ns_w    = (const float*)d_in[13];
  const float* We_ss   = (const float*)d_in[14];
  const float* We_vs   = (const float*)d_in[15];
  const float* We_sv   = (const float*)d_in[16];
  const float* We_vv   = (const float*)d_in[17];
  const float* We_vx   = (const float*)d_in[18];
  const float* Wmix_s  = (const float*)d_in[19];
  const float* Wmix_v  = (const float*)d_in[20];
  const float* Wself_s = (const float*)d_in[21];
  const float* Wself_v = (const float*)d_in[22];
  const float* skip_w  = (const float*)d_in[23];
  const float* skip_b  = (const float*)d_in[24];
  const float* w_out   = (const float*)d_in[25];
  const float* gain    = (const float*)d_in[26];

  char* ws = (char*)d_ws;
  size_t o = 0;
  auto alloc = [&](size_t bytes) -> void* {
    void* p = ws + o;
    o += (bytes + 255) & ~(size_t)255;
    return p;
  };
  float* s_feat  = (float*)alloc((size_t)NA * 64 * 4);
  ushort16* s_bf = (ushort16*)alloc((size_t)NA * 64 * 2);
  float* a_s     = (float*)alloc((size_t)NA * 96 * 4);
  float* a_v     = (float*)alloc((size_t)NA * 512 * 4);  // [n][128][4]; agg0 uses [n][64][4]
  float* sh0     = (float*)alloc((size_t)NA * 64 * 4);
  float* sh1     = (float*)alloc((size_t)NA * 64 * 4);
  ushort16* shbf0= (ushort16*)alloc((size_t)NA * 64 * 2);
  ushort16* shbf1= (ushort16*)alloc((size_t)NA * 64 * 2);
  float* vh0     = (float*)alloc((size_t)NA * 128 * 4);  // [n][32][4]
  float* vh1     = (float*)alloc((size_t)NA * 128 * 4);
  uint32* vhbf0  = (uint32*)alloc((size_t)NA * 64 * 4);  // [n][32][2] uints
  uint32* vhbf1  = (uint32*)alloc((size_t)NA * 64 * 4);
  int* count     = (int*)alloc((size_t)NA * 4);
  int* partial   = (int*)alloc((size_t)64 * 4);
  int* offsets   = (int*)alloc((size_t)(NA + 1) * 4);
  int* cursor    = (int*)alloc((size_t)NA * 4);
  float* rec8    = (float*)alloc((size_t)ET * 32);
  uint32* T0     = (uint32*)alloc((size_t)T0U * 4);
  uint32* TL     = (uint32*)alloc((size_t)2 * TLU * 4);
  float* shb[2]  = {sh0, sh1};
  ushort16* shbf[2] = {shbf0, shbf1};
  float* vhb[2]  = {vh0, vh1};
  uint32* vhbf[2]= {vhbf0, vhbf1};

  // CSR build + tables
  k_zero<<<NA / 256, 256, 0, stream>>>(count);
  k_hist<<<ET / 256, 256, 0, stream>>>(rad, bon, count);
  k_scan1<<<64, 256, 0, stream>>>(count, partial);
  k_scan2<<<1, 1, 0, stream>>>(partial);
  k_scan3<<<64, 256, 0, stream>>>(count, partial, offsets, cursor);
  k_fill_pre<<<ET / 256, 256, 0, stream>>>(rad, bon, cursor, pos, rec8);
  k_build<<<dim3(BINS, 3, 2), 64, 0, stream>>>(We0, We1, We_ss, We_vs, We_sv, We_vv, We_vx,
                                               bond_tab, T0, TL);

  k_embed<<<NA * 64 / 256, 256, 0, stream>>>(atom_tab, types, ns0_w, cn, s_feat, s_bf);
  k_agg0<<<NA / 4, 256, 0, stream>>>(offsets, rec8, T0, s_bf, a_s, a_v);
  k_init_s<<<NA / 8, 256, 0, stream>>>(a_s, s_feat, Ws0, Wself0, shb[0], shbf[0]);
  k_init_v<<<NA / 8, 256, 0, stream>>>(a_v, Wv0, vhb[0], vhbf[0]);

  for (int l = 0; l < 2; ++l) {
    int bin = l & 1, bout = 1 - bin;
    k_agg_layer<<<NA / 4, 256, 0, stream>>>(
        cn, ns_w + l * 96, offsets, rec8, TL + (size_t)l * TLU, shbf[bin], vhbf[bin], a_s, a_v);
    k_mix_s<<<NA / 8, 256, 0, stream>>>(
        a_s, shb[bin], Wmix_s + l * 96 * 64, Wself_s + l * 64 * 64,
        ns_w + l * 96, skip_w + l * 192, skip_b + l * 192, cn, shb[bout], shbf[bout]);
    k_mix_v<<<NA / 8, 256, 0, stream>>>(
        a_v, vhb[bin], Wmix_v + l * 128 * 32, Wself_v + l * 32 * 32,
        ns_w + l * 96, skip_w + l * 192, skip_b + l * 192, cn, vhb[bout], vhbf[bout]);
  }
  k_out<<<NA * 3 / 256, 256, 0, stream>>>(vhb[0], w_out, gain, (float*)d_out);
}